// Round 6
// baseline (1179.639 us; speedup 1.0000x reference)
//
#include <hip/hip_runtime.h>
#include <hip/hip_bf16.h>
#include <hip/hip_fp16.h>

typedef _Float16 half8 __attribute__((ext_vector_type(8)));
typedef _Float16 half4 __attribute__((ext_vector_type(4)));
typedef float floatx4 __attribute__((ext_vector_type(4)));

__device__ __forceinline__ _Float16 f2h(float f) { return (_Float16)f; }

// ---------------------------------------------------------------------------
// dummy-fill the padded edge arrays: src=N (zero row), g=NGT (zero emb row),
// dst=N (skip marker). wS4 is zeroed by memset.
// ---------------------------------------------------------------------------
__global__ void fill_dummy_kernel(int* __restrict__ srcS, int* __restrict__ dstS,
                                  int cap, int N, int NGT)
{
    int i = blockIdx.x * 256 + threadIdx.x;
    if (i < cap) { srcS[i] = N | (NGT << 24); dstS[i] = N; }
}

__global__ void hist_kernel(const int* __restrict__ dst, int* __restrict__ cnt, int E)
{
    int e = blockIdx.x * 256 + threadIdx.x;
    if (e < E) atomicAdd(&cnt[dst[e]], 1);
}

// exclusive scan of per-node counts PADDED to multiple of 4 -> offP
__global__ void scan1p_kernel(const int* __restrict__ cnt, int* __restrict__ offP,
                              int n, int* __restrict__ blockSums)
{
    __shared__ int sm[256];
    const int t = threadIdx.x;
    const int base = blockIdx.x * 1024 + t * 4;
    int v[4]; int s = 0;
#pragma unroll
    for (int i = 0; i < 4; ++i) {
        v[i] = (base + i < n) ? ((cnt[base + i] + 3) & ~3) : 0;
        s += v[i];
    }
    sm[t] = s; __syncthreads();
#pragma unroll
    for (int off = 1; off < 256; off <<= 1) {
        int y = (t >= off) ? sm[t - off] : 0;
        __syncthreads();
        if (t >= off) sm[t] += y;
        __syncthreads();
    }
    int excl = sm[t] - s;
    if (t == 255) blockSums[blockIdx.x] = sm[255];
    int run = excl;
#pragma unroll
    for (int i = 0; i < 4; ++i) {
        if (base + i < n) offP[base + i] = run;
        run += v[i];
    }
}

__global__ void scan2_kernel(int* __restrict__ blockSums, int nb)
{
    __shared__ int sm[256];
    const int t = threadIdx.x;
    int s = (t < nb) ? blockSums[t] : 0;
    sm[t] = s; __syncthreads();
#pragma unroll
    for (int off = 1; off < 256; off <<= 1) {
        int y = (t >= off) ? sm[t - off] : 0;
        __syncthreads();
        if (t >= off) sm[t] += y;
        __syncthreads();
    }
    if (t < nb) blockSums[t] = sm[t] - s;
}

__global__ void scan3_kernel(int* __restrict__ offP, int n, const int* __restrict__ blockSums)
{
    const int base = blockIdx.x * 1024 + threadIdx.x * 4;
    const int add = blockSums[blockIdx.x];
#pragma unroll
    for (int i = 0; i < 4; ++i)
        if (base + i < n) offP[base + i] += add;
}

__global__ void scatter_kernel(const int* __restrict__ src, const int* __restrict__ dst,
                               const float* __restrict__ w, const int* __restrict__ gt,
                               const int* __restrict__ offP, int* __restrict__ cur,
                               int* __restrict__ srcS, int* __restrict__ dstS,
                               half4* __restrict__ wS4, int E)
{
    int e = blockIdx.x * 256 + threadIdx.x;
    if (e >= E) return;
    int d = dst[e];
    int p = offP[d] + atomicAdd(&cur[d], 1);
    int s = src[e];
    srcS[p] = s | (gt[s] << 24);
    dstS[p] = d;
    half4 q;
    q[0] = f2h(w[(size_t)e * 3 + 0]);
    q[1] = f2h(w[(size_t)e * 3 + 1]);
    q[2] = f2h(w[(size_t)e * 3 + 2]);
    q[3] = (_Float16)1.0f;             // bias slot (k=131); pads stay 0 -> no bias
    wS4[p] = q;
}

// ---------------------------------------------------------------------------
// weight prep: W [K,128] fp32 -> out [128,KP] f16, optional bias at col 131
// ---------------------------------------------------------------------------
__global__ void wprep_kernel(const float* __restrict__ W, const float* __restrict__ bias,
                             _Float16* __restrict__ out, int K, int KP)
{
    int idx = blockIdx.x * 256 + threadIdx.x;
    if (idx >= 128 * KP) return;
    int f = idx / KP, k = idx % KP;
    float v = 0.0f;
    if (k < K) v = W[(size_t)k * 128 + f];
    else if (bias != nullptr && k == 131) v = bias[f];
    out[idx] = f2h(v);
}

// embW1b[g][f] = b1_0[f] + emb[g]@W1_0[:64]; row NGT = zeros (pad edges)
__global__ void embW1_kernel(const float* __restrict__ emb, const float* __restrict__ W1,
                             const float* __restrict__ b1, float* __restrict__ out, int NGT)
{
    int idx = blockIdx.x * 256 + threadIdx.x;
    if (idx >= (NGT + 1) * 128) return;
    int g = idx >> 7, f = idx & 127;
    float s = 0.0f;
    if (g < NGT) {
        s = b1[f];
        for (int k = 0; k < 64; ++k) s += emb[g * 64 + k] * W1[(size_t)k * 128 + f];
    }
    out[idx] = s;
}

__global__ void embW2_kernel(const float* __restrict__ emb, const float* __restrict__ W2,
                             float* __restrict__ out, int NGT)
{
    int idx = blockIdx.x * 256 + threadIdx.x;
    if (idx >= NGT * 128) return;
    int g = idx >> 7, f = idx & 127;
    float s = 0.0f;
    for (int k = 0; k < 64; ++k) s += emb[g * 64 + k] * W2[(size_t)k * 128 + f];
    out[idx] = s;
}

// ---------------------------------------------------------------------------
// group output helper (edge0): plain store if single-group dst, else atomic
// ---------------------------------------------------------------------------
template<bool H16>
__device__ __forceinline__ void outGroup(void* hNv, int dG, bool multi,
                                         const float (&v)[8], int lRow, int lane)
{
    if (H16) {
        __half* hN = (__half*)hNv;
#pragma unroll
        for (int jt = 0; jt < 8; ++jt) {
            float other = __shfl_xor(v[jt], 1);
            if ((lane & 1) == 0) {
                __half2 p = __halves2half2(__float2half(v[jt]), __float2half(other));
                __half2* addr = (__half2*)(hN + (size_t)dG * 128 + jt * 16 + lRow);
                if (multi) unsafeAtomicAdd(addr, p);
                else       *addr = p;
            }
        }
    } else {
        float* hN = (float*)hNv;
#pragma unroll
        for (int jt = 0; jt < 8; ++jt) {
            float* addr = hN + (size_t)dG * 128 + jt * 16 + lRow;
            if (multi) unsafeAtomicAdd(addr, v[jt]);
            else       *addr = v[jt];
        }
    }
}

// ---------------------------------------------------------------------------
// edge layer 0 (no MFMA): per group sum of relu(embW1b[g] + w@W1w) -> store
// ---------------------------------------------------------------------------
template<bool H16>
__global__ void __launch_bounds__(256, 4)
edge0_kernel(const float* __restrict__ embW1b, const float* __restrict__ W1_0,
             const int* __restrict__ srcS, const int* __restrict__ dstS,
             const half4* __restrict__ wS4,
             void* __restrict__ hNv, int N, int tilesPerWave, int eTiles4)
{
    const int tid  = threadIdx.x;
    const int lane = tid & 63;
    const int wv   = tid >> 6;
    const int lRow = lane & 15;
    const int lGrp = lane >> 4;

    float w1w[3][8];
#pragma unroll
    for (int c = 0; c < 3; ++c)
#pragma unroll
        for (int jt = 0; jt < 8; ++jt)
            w1w[c][jt] = W1_0[(size_t)(64 + c) * 128 + jt * 16 + lRow];

    const int wave = blockIdx.x * 4 + wv;
    const int t0 = wave * tilesPerWave;
    const int t1 = min(t0 + tilesPerWave, eTiles4);

    for (int tile = t0; tile < t1; ++tile) {
        const int e0 = tile * 16;
        if (dstS[e0] >= N) continue;           // all-dummy tail tile
        const int eb = e0 + lGrp * 4;
        const int dG = dstS[eb];
        int4 s4 = *(const int4*)(srcS + eb);
        const int sArr[4] = {s4.x, s4.y, s4.z, s4.w};

        float sum[8];
#pragma unroll
        for (int jt = 0; jt < 8; ++jt) sum[jt] = 0.0f;

#pragma unroll
        for (int r = 0; r < 4; ++r) {
            const int g = sArr[r] >> 24;       // NGT for pads -> zero row
            const half4 q = wS4[eb + r];
            const float w0 = (float)q[0], w1 = (float)q[1], w2 = (float)q[2];
            const float* e1 = embW1b + (size_t)g * 128;
#pragma unroll
            for (int jt = 0; jt < 8; ++jt) {
                float m = e1[jt * 16 + lRow]
                        + w0 * w1w[0][jt] + w1 * w1w[1][jt] + w2 * w1w[2][jt];
                sum[jt] += fmaxf(m, 0.0f);
            }
        }
        if (dG < N) {
            bool multi = ((eb >= 4 && dstS[eb - 4] == dG) || dstS[eb + 4] == dG);
            outGroup<H16>(hNv, dG, multi, sum, lRow, lane);
        }
    }
}

// ---------------------------------------------------------------------------
// edge layers 1,2 (MFMA): NO LDS. B (W1T) in registers; block's 4 waves split
// the 128 output cols (32 each) and walk the same tiles (gathers L1-shared).
// ---------------------------------------------------------------------------
template<bool H16>
__global__ void __launch_bounds__(256, 4)
edge_mfma_kernel(const _Float16* __restrict__ hA,   // [(N+1),128], row N = 0
                 const _Float16* __restrict__ W1T,  // [128,160] (w@128..130, bias@131)
                 const int* __restrict__ srcS, const int* __restrict__ dstS,
                 const half4* __restrict__ wS4,
                 void* __restrict__ hNv, int N, int tilesPerBlock, int eTiles4)
{
    const int tid  = threadIdx.x;
    const int lane = tid & 63;
    const int wv   = tid >> 6;       // wave owns output cols [wv*32, wv*32+32)
    const int lRow = lane & 15;
    const int lGrp = lane >> 4;

    // B fragments in registers: col = wv*32 + {0,16} + lRow ; k = kc*32 + lGrp*8
    half8 B0[5], B1[5];
    {
        const _Float16* b0 = W1T + (size_t)(wv * 32 + lRow) * 160 + lGrp * 8;
        const _Float16* b1 = W1T + (size_t)(wv * 32 + 16 + lRow) * 160 + lGrp * 8;
#pragma unroll
        for (int kc = 0; kc < 5; ++kc) {
            B0[kc] = *(const half8*)(b0 + kc * 32);
            B1[kc] = *(const half8*)(b1 + kc * 32);
        }
    }

    const int t0 = blockIdx.x * tilesPerBlock;
    const int t1 = min(t0 + tilesPerBlock, eTiles4);

    for (int tile = t0; tile < t1; ++tile) {
        const int e0 = tile * 16;
        if (dstS[e0] >= N) continue;           // all-dummy tail tile
        const int eA = e0 + lRow;
        const int s_ = srcS[eA] & 0xFFFFFF;    // pads -> row N (zeros)
        const half4 q = wS4[eA];

        half8 F[5];
#pragma unroll
        for (int kc = 0; kc < 4; ++kc)
            F[kc] = *(const half8*)(hA + (size_t)s_ * 128 + kc * 32 + lGrp * 8);
        {
            half8 aw = {};
            if (lGrp == 0) { aw[0] = q[0]; aw[1] = q[1]; aw[2] = q[2]; aw[3] = q[3]; }
            F[4] = aw;
        }

        floatx4 a0 = {}, a1 = {};
#pragma unroll
        for (int kc = 0; kc < 5; ++kc) {
            a0 = __builtin_amdgcn_mfma_f32_16x16x32_f16(F[kc], B0[kc], a0, 0, 0, 0);
            a1 = __builtin_amdgcn_mfma_f32_16x16x32_f16(F[kc], B1[kc], a1, 0, 0, 0);
        }

        const int eb = e0 + lGrp * 4;
        const int dG = dstS[eb];
        if (dG < N) {
            float s0 = fmaxf(a0[0], 0.f) + fmaxf(a0[1], 0.f)
                     + fmaxf(a0[2], 0.f) + fmaxf(a0[3], 0.f);
            float s1 = fmaxf(a1[0], 0.f) + fmaxf(a1[1], 0.f)
                     + fmaxf(a1[2], 0.f) + fmaxf(a1[3], 0.f);
            const bool multi = ((eb >= 4 && dstS[eb - 4] == dG) || dstS[eb + 4] == dG);
            if (H16) {
                __half* hN = (__half*)hNv;
                float o0 = __shfl_xor(s0, 1);
                float o1 = __shfl_xor(s1, 1);
                if ((lane & 1) == 0) {
                    __half2 p0 = __halves2half2(__float2half(s0), __float2half(o0));
                    __half2 p1 = __halves2half2(__float2half(s1), __float2half(o1));
                    __half2* q0 = (__half2*)(hN + (size_t)dG * 128 + wv * 32 + lRow);
                    __half2* q1 = (__half2*)(hN + (size_t)dG * 128 + wv * 32 + 16 + lRow);
                    if (multi) { unsafeAtomicAdd(q0, p0); unsafeAtomicAdd(q1, p1); }
                    else       { *q0 = p0; *q1 = p1; }
                }
            } else {
                float* hN = (float*)hNv;
                float* q0 = hN + (size_t)dG * 128 + wv * 32 + lRow;
                float* q1 = q0 + 16;
                if (multi) { unsafeAtomicAdd(q0, s0); unsafeAtomicAdd(q1, s1); }
                else       { *q0 = s0; *q1 = s1; }
            }
        }
    }
}

// ---------------------------------------------------------------------------
// node kernel: h = normalize(relu([h,]hN @ W2 [+ embW2[gt]])); readout
// ---------------------------------------------------------------------------
template<bool H16, bool L0, bool LAST>
__global__ void __launch_bounds__(512, 2)
node_kernel(const _Float16* __restrict__ hA,    // [N,128] (unused if L0)
            const void* __restrict__ hNv,       // [N,128] f16 or f32
            const _Float16* __restrict__ W2T,   // [128,K2]
            const float* __restrict__ embW2,    // [30,128] (L0 only)
            const int* __restrict__ gt,         // (L0 only)
            const int* __restrict__ n2g,
            _Float16* __restrict__ hOut,        // if !LAST
            float* __restrict__ fOut,           // if LAST
            float* __restrict__ readout,
            int N, int tilesPerWave, int nTiles, int layerOff)
{
    constexpr int K2  = L0 ? 128 : 256;
    constexpr int KCA = L0 ? 0 : 4;
    constexpr int KC  = K2 / 32;
    constexpr int SPR = K2 / 8;
    __shared__ __align__(16) _Float16 lds[128 * K2];

    const int tid = threadIdx.x;
    for (int s = tid; s < 128 * SPR; s += 512) {
        const int row = s / SPR, seg = s % SPR;
        half8 v = *(const half8*)(W2T + (size_t)row * K2 + seg * 8);
        *(half8*)(&lds[row * K2 + ((seg ^ (row & 7)) * 8)]) = v;
    }
    __syncthreads();

    const int lane = tid & 63;
    const int wv   = tid >> 6;
    const int lRow = lane & 15;
    const int lGrp = lane >> 4;
    const int wave = blockIdx.x * 8 + wv;
    const int t0 = wave * tilesPerWave;
    const int t1 = min(t0 + tilesPerWave, nTiles);
    if (t0 >= t1) return;

    int gCur = -1; float racc[8];
#pragma unroll
    for (int jt = 0; jt < 8; ++jt) racc[jt] = 0.0f;

    for (int tile = t0; tile < t1; ++tile) {
        const int i0 = tile * 16;
        const int iA = min(i0 + lRow, N - 1);

        half8 afrag[KC];
#pragma unroll
        for (int kc = 0; kc < KCA; ++kc)
            afrag[kc] = *(const half8*)(hA + (size_t)iA * 128 + kc * 32 + lGrp * 8);
        if (H16) {
            const _Float16* hN = (const _Float16*)hNv;
#pragma unroll
            for (int kc = KCA; kc < KC; ++kc)
                afrag[kc] = *(const half8*)(hN + (size_t)iA * 128 + (kc - KCA) * 32 + lGrp * 8);
        } else {
            const float* hN = (const float*)hNv;
#pragma unroll
            for (int kc = KCA; kc < KC; ++kc) {
                const float* p = hN + (size_t)iA * 128 + (kc - KCA) * 32 + lGrp * 8;
                floatx4 f0 = *(const floatx4*)(p);
                floatx4 f1 = *(const floatx4*)(p + 4);
                half8 a;
#pragma unroll
                for (int i = 0; i < 4; ++i) { a[i] = f2h(f0[i]); a[i + 4] = f2h(f1[i]); }
                afrag[kc] = a;
            }
        }

        floatx4 acc[8] = {};
#pragma unroll
        for (int jt = 0; jt < 8; ++jt) {
            const int rb = (jt * 16 + lRow) * K2;
            const int sw = (jt * 16 + lRow) & 7;
#pragma unroll
            for (int kc = 0; kc < KC; ++kc) {
                half8 b = *(const half8*)(&lds[rb + (((kc * 4 + lGrp) ^ sw) * 8)]);
                acc[jt] = __builtin_amdgcn_mfma_f32_16x16x32_f16(afrag[kc], b, acc[jt], 0, 0, 0);
            }
        }

        if (L0) {
#pragma unroll
            for (int r = 0; r < 4; ++r) {
                const int i = min(i0 + lGrp * 4 + r, N - 1);
                const int g_t = gt[i];
#pragma unroll
                for (int jt = 0; jt < 8; ++jt)
                    acc[jt][r] += embW2[(size_t)g_t * 128 + jt * 16 + lRow];
            }
        }

        float scl[4];
#pragma unroll
        for (int r = 0; r < 4; ++r) {
            float s = 0.f;
#pragma unroll
            for (int jt = 0; jt < 8; ++jt) {
                float v = fmaxf(acc[jt][r], 0.0f);
                s += v * v;
            }
#pragma unroll
            for (int m = 1; m <= 8; m <<= 1) s += __shfl_xor(s, m);
            scl[r] = 1.0f / fmaxf(sqrtf(s), 1e-12f);
        }

#pragma unroll
        for (int r = 0; r < 4; ++r) {
            const int i = i0 + lGrp * 4 + r;
            if (i < N) {
#pragma unroll
                for (int jt = 0; jt < 8; ++jt) {
                    float v = fmaxf(acc[jt][r], 0.0f) * scl[r];
                    if (LAST) fOut[(size_t)i * 128 + jt * 16 + lRow] = v;
                    else      hOut[(size_t)i * 128 + jt * 16 + lRow] = f2h(v);
                }
            }
        }

        const int gFirst = n2g[min(i0, N - 1)];
        const int gLast  = n2g[min(i0 + 15, N - 1)];
        if (gFirst == gLast && i0 + 15 < N) {
            if (gFirst != gCur) {
                if (gCur >= 0 && lane < 16) {
#pragma unroll
                    for (int jt = 0; jt < 8; ++jt)
                        unsafeAtomicAdd(&readout[(size_t)gCur * 384 + layerOff + jt * 16 + lane], racc[jt]);
                }
                gCur = gFirst;
#pragma unroll
                for (int jt = 0; jt < 8; ++jt) racc[jt] = 0.0f;
            }
#pragma unroll
            for (int jt = 0; jt < 8; ++jt) {
                float t = 0.f;
#pragma unroll
                for (int r = 0; r < 4; ++r) t += fmaxf(acc[jt][r], 0.0f) * scl[r];
                t += __shfl_xor(t, 16);
                t += __shfl_xor(t, 32);
                racc[jt] += t;
            }
        } else {
            if (gCur >= 0 && lane < 16) {
#pragma unroll
                for (int jt = 0; jt < 8; ++jt)
                    unsafeAtomicAdd(&readout[(size_t)gCur * 384 + layerOff + jt * 16 + lane], racc[jt]);
            }
            gCur = -1;
#pragma unroll
            for (int jt = 0; jt < 8; ++jt) racc[jt] = 0.0f;
#pragma unroll
            for (int r = 0; r < 4; ++r) {
                const int i = i0 + lGrp * 4 + r;
                if (i < N) {
                    const int g = n2g[i];
#pragma unroll
                    for (int jt = 0; jt < 8; ++jt) {
                        float v = fmaxf(acc[jt][r], 0.0f) * scl[r];
                        unsafeAtomicAdd(&readout[(size_t)g * 384 + layerOff + jt * 16 + lRow], v);
                    }
                }
            }
        }
    }
    if (gCur >= 0 && lane < 16) {
#pragma unroll
        for (int jt = 0; jt < 8; ++jt)
            unsafeAtomicAdd(&readout[(size_t)gCur * 384 + layerOff + jt * 16 + lane], racc[jt]);
    }
}

// ---------------------------------------------------------------------------
extern "C" void kernel_launch(void* const* d_in, const int* in_sizes, int n_in,
                              void* d_out, int out_size, void* d_ws, size_t ws_size,
                              hipStream_t stream)
{
    const int*   gate_type = (const int*)d_in[0];
    const int*   src  = (const int*)d_in[1];
    const int*   dst  = (const int*)d_in[2];
    const float* wE   = (const float*)d_in[3];
    const int*   n2g  = (const int*)d_in[4];
    const float* emb  = (const float*)d_in[5];
    const float* W1_0 = (const float*)d_in[6];
    const float* b1_0 = (const float*)d_in[7];
    const float* W2_0 = (const float*)d_in[8];
    const float* W1_1 = (const float*)d_in[9];
    const float* b1_1 = (const float*)d_in[10];
    const float* W2_1 = (const float*)d_in[11];
    const float* W1_2 = (const float*)d_in[12];
    const float* b1_2 = (const float*)d_in[13];
    const float* W2_2 = (const float*)d_in[14];

    const int N = in_sizes[0];
    const int E = in_sizes[1];
    const int NGT = in_sizes[5] / 64;
    const int cap = (E + 3 * N + 15) & ~15;       // padded edge-slot capacity

    char* ws = (char*)d_ws;
    size_t off = 0;
    auto alloc = [&](size_t bytes) { void* p = ws + off; off = (off + bytes + 255) & ~255ULL; return p; };
    _Float16* hBuf  = (_Float16*)alloc(((size_t)N + 1) * 128 * 2);
    int*      srcS  = (int*)alloc(((size_t)cap + 16) * 4);
    int*      dstS  = (int*)alloc(((size_t)cap + 16) * 4);
    half4*    wS4   = (half4*)alloc(((size_t)cap + 16) * 8);
    int*      cnt   = (int*)alloc((size_t)N * 4);
    int*      offP  = (int*)alloc((size_t)N * 4);
    int*      cur   = (int*)alloc((size_t)N * 4);
    int*      bSums = (int*)alloc(256 * 4);
    _Float16* W1T1  = (_Float16*)alloc((size_t)128 * 160 * 2);
    _Float16* W1T2  = (_Float16*)alloc((size_t)128 * 160 * 2);
    _Float16* W2T0  = (_Float16*)alloc((size_t)128 * 128 * 2);
    _Float16* W2T1  = (_Float16*)alloc((size_t)128 * 256 * 2);
    _Float16* W2T2  = (_Float16*)alloc((size_t)128 * 256 * 2);
    float*    eW1b  = (float*)alloc((size_t)(NGT + 1) * 128 * 4);
    float*    eW2   = (float*)alloc((size_t)NGT * 128 * 4);
    size_t hn16_off = off;
    const bool h16 = (ws_size >= hn16_off + ((size_t)N + 1) * 128 * 2 + 256);
    _Float16* hN16 = (_Float16*)alloc(((size_t)N + 1) * 128 * 2);  // only if h16

    float* readout = (float*)d_out + (size_t)N * 128;  // [G,384]
    void*  hN      = h16 ? (void*)hN16 : (void*)d_out; // fp32 fallback in d_out

    const int eTiles4 = cap / 16;
    const int nTiles  = (N + 15) / 16;
    const int EB = 1024;                                // edge blocks (4 waves ea)
    const int tpbE = (eTiles4 + EB - 1) / EB;           // tiles per BLOCK (col-split)
    const int tpwE0 = (eTiles4 + EB * 4 - 1) / (EB * 4);// edge0: tiles per wave
    const int NB = 256;                                 // node blocks, 8 waves ea
    const int tpwN = (nTiles + NB * 8 - 1) / (NB * 8);
    const int nb = (N + 1023) / 1024;

    // ---- init + counting sort (padded to 4 per dst) ----
    hipMemsetAsync(cnt, 0, (size_t)N * 4, stream);
    hipMemsetAsync(cur, 0, (size_t)N * 4, stream);
    hipMemsetAsync(wS4, 0, ((size_t)cap + 16) * 8, stream);
    hipMemsetAsync(hBuf + (size_t)N * 128, 0, 256, stream);   // zero row N
    fill_dummy_kernel<<<(cap + 16 + 255) / 256, 256, 0, stream>>>(srcS, dstS, cap + 16, N, NGT);
    hist_kernel<<<(E + 255) / 256, 256, 0, stream>>>(dst, cnt, E);
    scan1p_kernel<<<nb, 256, 0, stream>>>(cnt, offP, N, bSums);
    scan2_kernel<<<1, 256, 0, stream>>>(bSums, nb);
    scan3_kernel<<<nb, 256, 0, stream>>>(offP, N, bSums);
    scatter_kernel<<<(E + 255) / 256, 256, 0, stream>>>(src, dst, wE, gate_type,
                                                        offP, cur, srcS, dstS, wS4, E);

    // ---- weight prep ----
    embW1_kernel<<<((NGT + 1) * 128 + 255) / 256, 256, 0, stream>>>(emb, W1_0, b1_0, eW1b, NGT);
    embW2_kernel<<<(NGT * 128 + 255) / 256, 256, 0, stream>>>(emb, W2_0, eW2, NGT);
    wprep_kernel<<<(128 * 160 + 255) / 256, 256, 0, stream>>>(W1_1, b1_1, W1T1, 131, 160);
    wprep_kernel<<<(128 * 160 + 255) / 256, 256, 0, stream>>>(W1_2, b1_2, W1T2, 131, 160);
    wprep_kernel<<<(128 * 128 + 255) / 256, 256, 0, stream>>>(W2_0 + (size_t)64 * 128, nullptr, W2T0, 128, 128);
    wprep_kernel<<<(128 * 256 + 255) / 256, 256, 0, stream>>>(W2_1, nullptr, W2T1, 256, 256);
    wprep_kernel<<<(128 * 256 + 255) / 256, 256, 0, stream>>>(W2_2, nullptr, W2T2, 256, 256);

    if (h16) {
        hipMemsetAsync(readout, 0, (size_t)(out_size - N * 128) * 4, stream);
        hipMemsetAsync(hN16, 0, ((size_t)N + 1) * 128 * 2, stream);
        // layer 0
        edge0_kernel<true><<<EB, 256, 0, stream>>>(eW1b, W1_0, srcS, dstS, wS4, hN, N, tpwE0, eTiles4);
        node_kernel<true, true, false><<<NB, 512, 0, stream>>>(nullptr, hN, W2T0, eW2, gate_type, n2g,
                                                               hBuf, nullptr, readout, N, tpwN, nTiles, 0);
        hipMemsetAsync(hN16, 0, ((size_t)N + 1) * 128 * 2, stream);
        // layer 1
        edge_mfma_kernel<true><<<EB, 256, 0, stream>>>(hBuf, W1T1, srcS, dstS, wS4, hN, N, tpbE, eTiles4);
        node_kernel<true, false, false><<<NB, 512, 0, stream>>>(hBuf, hN, W2T1, nullptr, nullptr, n2g,
                                                                hBuf, nullptr, readout, N, tpwN, nTiles, 128);
        hipMemsetAsync(hN16, 0, ((size_t)N + 1) * 128 * 2, stream);
        // layer 2 (final fp32 h straight to d_out)
        edge_mfma_kernel<true><<<EB, 256, 0, stream>>>(hBuf, W1T2, srcS, dstS, wS4, hN, N, tpbE, eTiles4);
        node_kernel<true, false, true><<<NB, 512, 0, stream>>>(hBuf, hN, W2T2, nullptr, nullptr, n2g,
                                                               nullptr, (float*)d_out, readout, N, tpwN, nTiles, 256);
    } else {
        hipMemsetAsync(d_out, 0, (size_t)out_size * 4, stream);
        // layer 0
        edge0_kernel<false><<<EB, 256, 0, stream>>>(eW1b, W1_0, srcS, dstS, wS4, hN, N, tpwE0, eTiles4);
        node_kernel<false, true, false><<<NB, 512, 0, stream>>>(nullptr, hN, W2T0, eW2, gate_type, n2g,
                                                                hBuf, nullptr, readout, N, tpwN, nTiles, 0);
        hipMemsetAsync(d_out, 0, (size_t)N * 128 * 4, stream);
        // layer 1
        edge_mfma_kernel<false><<<EB, 256, 0, stream>>>(hBuf, W1T1, srcS, dstS, wS4, hN, N, tpbE, eTiles4);
        node_kernel<false, false, false><<<NB, 512, 0, stream>>>(hBuf, hN, W2T1, nullptr, nullptr, n2g,
                                                                 hBuf, nullptr, readout, N, tpwN, nTiles, 128);
        hipMemsetAsync(d_out, 0, (size_t)N * 128 * 4, stream);
        // layer 2 (in-place over hN = d_out)
        edge_mfma_kernel<false><<<EB, 256, 0, stream>>>(hBuf, W1T2, srcS, dstS, wS4, hN, N, tpbE, eTiles4);
        node_kernel<false, false, true><<<NB, 512, 0, stream>>>(hBuf, hN, W2T2, nullptr, nullptr, n2g,
                                                                nullptr, (float*)d_out, readout, N, tpwN, nTiles, 256);
    }
}

// Round 7
// 756.917 us; speedup vs baseline: 1.5585x; 1.5585x over previous
//
#include <hip/hip_runtime.h>
#include <hip/hip_bf16.h>
#include <hip/hip_fp16.h>

typedef _Float16 half8 __attribute__((ext_vector_type(8)));
typedef _Float16 half4 __attribute__((ext_vector_type(4)));
typedef float floatx4 __attribute__((ext_vector_type(4)));

__device__ __forceinline__ _Float16 f2h(float f) { return (_Float16)f; }

// ---------------------------------------------------------------------------
// dummy-fill padded edge arrays: src=N (zero row), g=NGT (zero emb row),
// dst=N (skip marker). wS4 zeroed by memset.
// ---------------------------------------------------------------------------
__global__ void fill_dummy_kernel(int* __restrict__ srcS, int* __restrict__ dstS,
                                  int cap, int N, int NGT)
{
    int i = blockIdx.x * 256 + threadIdx.x;
    if (i < cap) { srcS[i] = N | (NGT << 24); dstS[i] = N; }
}

__global__ void hist_kernel(const int* __restrict__ dst, int* __restrict__ cnt, int E)
{
    int e = blockIdx.x * 256 + threadIdx.x;
    if (e < E) atomicAdd(&cnt[dst[e]], 1);
}

// exclusive scan of per-node counts PADDED to multiple of 4 -> offP
__global__ void scan1p_kernel(const int* __restrict__ cnt, int* __restrict__ offP,
                              int n, int* __restrict__ blockSums)
{
    __shared__ int sm[256];
    const int t = threadIdx.x;
    const int base = blockIdx.x * 1024 + t * 4;
    int v[4]; int s = 0;
#pragma unroll
    for (int i = 0; i < 4; ++i) {
        v[i] = (base + i < n) ? ((cnt[base + i] + 3) & ~3) : 0;
        s += v[i];
    }
    sm[t] = s; __syncthreads();
#pragma unroll
    for (int off = 1; off < 256; off <<= 1) {
        int y = (t >= off) ? sm[t - off] : 0;
        __syncthreads();
        if (t >= off) sm[t] += y;
        __syncthreads();
    }
    int excl = sm[t] - s;
    if (t == 255) blockSums[blockIdx.x] = sm[255];
    int run = excl;
#pragma unroll
    for (int i = 0; i < 4; ++i) {
        if (base + i < n) offP[base + i] = run;
        run += v[i];
    }
}

__global__ void scan2_kernel(int* __restrict__ blockSums, int nb)
{
    __shared__ int sm[256];
    const int t = threadIdx.x;
    int s = (t < nb) ? blockSums[t] : 0;
    sm[t] = s; __syncthreads();
#pragma unroll
    for (int off = 1; off < 256; off <<= 1) {
        int y = (t >= off) ? sm[t - off] : 0;
        __syncthreads();
        if (t >= off) sm[t] += y;
        __syncthreads();
    }
    if (t < nb) blockSums[t] = sm[t] - s;
}

__global__ void scan3_kernel(int* __restrict__ offP, int n, const int* __restrict__ blockSums)
{
    const int base = blockIdx.x * 1024 + threadIdx.x * 4;
    const int add = blockSums[blockIdx.x];
#pragma unroll
    for (int i = 0; i < 4; ++i)
        if (base + i < n) offP[base + i] += add;
}

__global__ void scatter_kernel(const int* __restrict__ src, const int* __restrict__ dst,
                               const float* __restrict__ w, const int* __restrict__ gt,
                               const int* __restrict__ offP, int* __restrict__ cur,
                               int* __restrict__ srcS, int* __restrict__ dstS,
                               half4* __restrict__ wS4, int E)
{
    int e = blockIdx.x * 256 + threadIdx.x;
    if (e >= E) return;
    int d = dst[e];
    int p = offP[d] + atomicAdd(&cur[d], 1);
    int s = src[e];
    srcS[p] = s | (gt[s] << 24);
    dstS[p] = d;
    half4 q;
    q[0] = f2h(w[(size_t)e * 3 + 0]);
    q[1] = f2h(w[(size_t)e * 3 + 1]);
    q[2] = f2h(w[(size_t)e * 3 + 2]);
    q[3] = (_Float16)1.0f;
    wS4[p] = q;
}

// ---------------------------------------------------------------------------
// weight prep: W [K,128] fp32 -> out [128,KP] f16 (outcol-major, k minor)
// ---------------------------------------------------------------------------
__global__ void wprep_kernel(const float* __restrict__ W, _Float16* __restrict__ out,
                             int K, int KP)
{
    int idx = blockIdx.x * 256 + threadIdx.x;
    if (idx >= 128 * KP) return;
    int f = idx / KP, k = idx % KP;
    float v = (k < K) ? W[(size_t)k * 128 + f] : 0.0f;
    out[idx] = f2h(v);
}

// embW1b[g][f] = b1_0[f] + emb[g]@W1_0[:64] (f16); row NGT = zeros (pads)
__global__ void embW1_kernel(const float* __restrict__ emb, const float* __restrict__ W1,
                             const float* __restrict__ b1, _Float16* __restrict__ out, int NGT)
{
    int idx = blockIdx.x * 256 + threadIdx.x;
    if (idx >= (NGT + 1) * 128) return;
    int g = idx >> 7, f = idx & 127;
    float s = 0.0f;
    if (g < NGT) {
        s = b1[f];
        for (int k = 0; k < 64; ++k) s += emb[g * 64 + k] * W1[(size_t)k * 128 + f];
    }
    out[idx] = f2h(s);
}

__global__ void embW2_kernel(const float* __restrict__ emb, const float* __restrict__ W2,
                             float* __restrict__ out, int NGT)
{
    int idx = blockIdx.x * 256 + threadIdx.x;
    if (idx >= NGT * 128) return;
    int g = idx >> 7, f = idx & 127;
    float s = 0.0f;
    for (int k = 0; k < 64; ++k) s += emb[g * 64 + k] * W2[(size_t)k * 128 + f];
    out[idx] = s;
}

// ---------------------------------------------------------------------------
// hW1b = h @ W1[:128] + b1  (dense, per-node; feeds the edge kernel)
// ---------------------------------------------------------------------------
__global__ void __launch_bounds__(512, 2)
hw1_kernel(const _Float16* __restrict__ hA,   // [N,128]
           const _Float16* __restrict__ WT,   // [128 outcol, 128 k] f16
           const float* __restrict__ b1,
           _Float16* __restrict__ out,        // [(N+1),128]
           int N, int tilesPerWave, int nTiles)
{
    __shared__ __align__(16) _Float16 lds[128 * 128];
    const int tid = threadIdx.x;
    for (int s = tid; s < 128 * 16; s += 512) {
        const int row = s / 16, seg = s % 16;
        half8 v = *(const half8*)(WT + (size_t)row * 128 + seg * 8);
        *(half8*)(&lds[row * 128 + ((seg ^ (row & 7)) * 8)]) = v;
    }
    __syncthreads();

    const int lane = tid & 63;
    const int wv   = tid >> 6;
    const int lRow = lane & 15;
    const int lGrp = lane >> 4;

    float b1v[8];
#pragma unroll
    for (int jt = 0; jt < 8; ++jt) b1v[jt] = b1[jt * 16 + lRow];

    const int wave = blockIdx.x * 8 + wv;
    const int t0 = wave * tilesPerWave;
    const int t1 = min(t0 + tilesPerWave, nTiles);

    for (int tile = t0; tile < t1; ++tile) {
        const int i0 = tile * 16;
        const int iA = min(i0 + lRow, N - 1);
        half8 a[4];
#pragma unroll
        for (int kc = 0; kc < 4; ++kc)
            a[kc] = *(const half8*)(hA + (size_t)iA * 128 + kc * 32 + lGrp * 8);

        floatx4 acc[8] = {};
#pragma unroll
        for (int jt = 0; jt < 8; ++jt) {
            const int row = jt * 16 + lRow;
            const int sw = row & 7;
#pragma unroll
            for (int kc = 0; kc < 4; ++kc) {
                half8 b = *(const half8*)(&lds[row * 128 + (((kc * 4 + lGrp) ^ sw) * 8)]);
                acc[jt] = __builtin_amdgcn_mfma_f32_16x16x32_f16(a[kc], b, acc[jt], 0, 0, 0);
            }
        }
#pragma unroll
        for (int r = 0; r < 4; ++r) {
            const int i = i0 + lGrp * 4 + r;
            if (i < N) {
#pragma unroll
                for (int jt = 0; jt < 8; ++jt)
                    out[(size_t)i * 128 + jt * 16 + lRow] = f2h(acc[jt][r] + b1v[jt]);
            }
        }
    }
}

// ---------------------------------------------------------------------------
// edge kernel (ALL layers, no MFMA): per 4-edge group,
//   t_e = relu(T[row(e)] + w_e @ Ww),  hN[dst] = sum_e t_e
// lane = (edge-pair sub, 4 cols); gather is coalesced 256B row reads.
// ---------------------------------------------------------------------------
template<bool L0, bool H16>
__global__ void __launch_bounds__(256, 8)
edgeW_kernel(const _Float16* __restrict__ T,    // embW1b (L0) or hW1b [(rows),128]
             const float* __restrict__ Ww,      // W1 w-rows [3][128] fp32
             const int* __restrict__ srcS, const int* __restrict__ dstS,
             const half4* __restrict__ wS4,
             void* __restrict__ hNv, int N, int groupsPerWave, int nGroups)
{
    const int tid  = threadIdx.x;
    const int lane = tid & 63;
    const int wv   = tid >> 6;
    const int sub  = lane >> 5;          // 0/1: edge within pair
    const int col4 = (lane & 31) * 4;    // 4 consecutive output cols

    float w0c[4], w1c[4], w2c[4];
#pragma unroll
    for (int c = 0; c < 4; ++c) {
        w0c[c] = Ww[0 * 128 + col4 + c];
        w1c[c] = Ww[1 * 128 + col4 + c];
        w2c[c] = Ww[2 * 128 + col4 + c];
    }

    const int wave = blockIdx.x * 4 + wv;
    const int g0 = wave * groupsPerWave;
    const int g1 = min(g0 + groupsPerWave, nGroups);

    for (int g = g0; g < g1; ++g) {
        const int eb = g * 4;
        const int dG = dstS[eb];
        if (dG >= N) continue;                    // dummy tail group
        const int sa = srcS[eb + sub];
        const int sb = srcS[eb + 2 + sub];
        const int ra = L0 ? (sa >> 24) : (sa & 0xFFFFFF);
        const int rb = L0 ? (sb >> 24) : (sb & 0xFFFFFF);
        const half4 qa = wS4[eb + sub];
        const half4 qb = wS4[eb + 2 + sub];
        const half4 va = *(const half4*)(T + (size_t)ra * 128 + col4);
        const half4 vb = *(const half4*)(T + (size_t)rb * 128 + col4);
        const float wa0 = (float)qa[0], wa1 = (float)qa[1], wa2 = (float)qa[2];
        const float wb0 = (float)qb[0], wb1 = (float)qb[1], wb2 = (float)qb[2];
        float r[4];
#pragma unroll
        for (int c = 0; c < 4; ++c) {
            float ma = (float)va[c] + wa0 * w0c[c] + wa1 * w1c[c] + wa2 * w2c[c];
            float mb = (float)vb[c] + wb0 * w0c[c] + wb1 * w1c[c] + wb2 * w2c[c];
            r[c] = fmaxf(ma, 0.0f) + fmaxf(mb, 0.0f);
        }
#pragma unroll
        for (int c = 0; c < 4; ++c) r[c] += __shfl_xor(r[c], 32);

        const bool multi = ((eb >= 4 && dstS[eb - 4] == dG) || dstS[eb + 4] == dG);
        if (lane < 32) {
            if (H16) {
                __half2 p0 = __halves2half2(__float2half(r[0]), __float2half(r[1]));
                __half2 p1 = __halves2half2(__float2half(r[2]), __float2half(r[3]));
                __half2* a0 = (__half2*)((__half*)hNv + (size_t)dG * 128 + col4);
                if (multi) { unsafeAtomicAdd(a0, p0); unsafeAtomicAdd(a0 + 1, p1); }
                else       { a0[0] = p0; a0[1] = p1; }
            } else {
                float* a0 = (float*)hNv + (size_t)dG * 128 + col4;
                if (multi) {
#pragma unroll
                    for (int c = 0; c < 4; ++c) unsafeAtomicAdd(a0 + c, r[c]);
                } else {
                    floatx4 p = {r[0], r[1], r[2], r[3]};
                    *(floatx4*)a0 = p;
                }
            }
        }
    }
}

// ---------------------------------------------------------------------------
// node kernel: h = normalize(relu([h,]hN @ W2 [+ embW2[gt]])); readout
// ---------------------------------------------------------------------------
template<bool H16, bool L0, bool LAST>
__global__ void __launch_bounds__(512, 2)
node_kernel(const _Float16* __restrict__ hA,    // [N,128] (unused if L0)
            const void* __restrict__ hNv,       // [N,128] f16 or f32
            const _Float16* __restrict__ W2T,   // [128,K2]
            const float* __restrict__ embW2,    // [30,128] (L0 only)
            const int* __restrict__ gt,         // (L0 only)
            const int* __restrict__ n2g,
            _Float16* __restrict__ hOut,        // if !LAST
            float* __restrict__ fOut,           // if LAST
            float* __restrict__ readout,
            int N, int tilesPerWave, int nTiles, int layerOff)
{
    constexpr int K2  = L0 ? 128 : 256;
    constexpr int KCA = L0 ? 0 : 4;
    constexpr int KC  = K2 / 32;
    constexpr int SPR = K2 / 8;
    __shared__ __align__(16) _Float16 lds[128 * K2];

    const int tid = threadIdx.x;
    for (int s = tid; s < 128 * SPR; s += 512) {
        const int row = s / SPR, seg = s % SPR;
        half8 v = *(const half8*)(W2T + (size_t)row * K2 + seg * 8);
        *(half8*)(&lds[row * K2 + ((seg ^ (row & 7)) * 8)]) = v;
    }
    __syncthreads();

    const int lane = tid & 63;
    const int wv   = tid >> 6;
    const int lRow = lane & 15;
    const int lGrp = lane >> 4;
    const int wave = blockIdx.x * 8 + wv;
    const int t0 = wave * tilesPerWave;
    const int t1 = min(t0 + tilesPerWave, nTiles);
    if (t0 >= t1) return;

    int gCur = -1; float racc[8];
#pragma unroll
    for (int jt = 0; jt < 8; ++jt) racc[jt] = 0.0f;

    for (int tile = t0; tile < t1; ++tile) {
        const int i0 = tile * 16;
        const int iA = min(i0 + lRow, N - 1);

        half8 afrag[KC];
#pragma unroll
        for (int kc = 0; kc < KCA; ++kc)
            afrag[kc] = *(const half8*)(hA + (size_t)iA * 128 + kc * 32 + lGrp * 8);
        if (H16) {
            const _Float16* hN = (const _Float16*)hNv;
#pragma unroll
            for (int kc = KCA; kc < KC; ++kc)
                afrag[kc] = *(const half8*)(hN + (size_t)iA * 128 + (kc - KCA) * 32 + lGrp * 8);
        } else {
            const float* hN = (const float*)hNv;
#pragma unroll
            for (int kc = KCA; kc < KC; ++kc) {
                const float* p = hN + (size_t)iA * 128 + (kc - KCA) * 32 + lGrp * 8;
                floatx4 f0 = *(const floatx4*)(p);
                floatx4 f1 = *(const floatx4*)(p + 4);
                half8 a;
#pragma unroll
                for (int i = 0; i < 4; ++i) { a[i] = f2h(f0[i]); a[i + 4] = f2h(f1[i]); }
                afrag[kc] = a;
            }
        }

        floatx4 acc[8] = {};
#pragma unroll
        for (int jt = 0; jt < 8; ++jt) {
            const int rb = (jt * 16 + lRow) * K2;
            const int sw = (jt * 16 + lRow) & 7;
#pragma unroll
            for (int kc = 0; kc < KC; ++kc) {
                half8 b = *(const half8*)(&lds[rb + (((kc * 4 + lGrp) ^ sw) * 8)]);
                acc[jt] = __builtin_amdgcn_mfma_f32_16x16x32_f16(afrag[kc], b, acc[jt], 0, 0, 0);
            }
        }

        if (L0) {
#pragma unroll
            for (int r = 0; r < 4; ++r) {
                const int i = min(i0 + lGrp * 4 + r, N - 1);
                const int g_t = gt[i];
#pragma unroll
                for (int jt = 0; jt < 8; ++jt)
                    acc[jt][r] += embW2[(size_t)g_t * 128 + jt * 16 + lRow];
            }
        }

        float scl[4];
#pragma unroll
        for (int r = 0; r < 4; ++r) {
            float s = 0.f;
#pragma unroll
            for (int jt = 0; jt < 8; ++jt) {
                float v = fmaxf(acc[jt][r], 0.0f);
                s += v * v;
            }
#pragma unroll
            for (int m = 1; m <= 8; m <<= 1) s += __shfl_xor(s, m);
            scl[r] = 1.0f / fmaxf(sqrtf(s), 1e-12f);
        }

#pragma unroll
        for (int r = 0; r < 4; ++r) {
            const int i = i0 + lGrp * 4 + r;
            if (i < N) {
#pragma unroll
                for (int jt = 0; jt < 8; ++jt) {
                    float v = fmaxf(acc[jt][r], 0.0f) * scl[r];
                    if (LAST) fOut[(size_t)i * 128 + jt * 16 + lRow] = v;
                    else      hOut[(size_t)i * 128 + jt * 16 + lRow] = f2h(v);
                }
            }
        }

        const int gFirst = n2g[min(i0, N - 1)];
        const int gLast  = n2g[min(i0 + 15, N - 1)];
        if (gFirst == gLast && i0 + 15 < N) {
            if (gFirst != gCur) {
                if (gCur >= 0 && lane < 16) {
#pragma unroll
                    for (int jt = 0; jt < 8; ++jt)
                        unsafeAtomicAdd(&readout[(size_t)gCur * 384 + layerOff + jt * 16 + lane], racc[jt]);
                }
                gCur = gFirst;
#pragma unroll
                for (int jt = 0; jt < 8; ++jt) racc[jt] = 0.0f;
            }
#pragma unroll
            for (int jt = 0; jt < 8; ++jt) {
                float t = 0.f;
#pragma unroll
                for (int r = 0; r < 4; ++r) t += fmaxf(acc[jt][r], 0.0f) * scl[r];
                t += __shfl_xor(t, 16);
                t += __shfl_xor(t, 32);
                racc[jt] += t;
            }
        } else {
            if (gCur >= 0 && lane < 16) {
#pragma unroll
                for (int jt = 0; jt < 8; ++jt)
                    unsafeAtomicAdd(&readout[(size_t)gCur * 384 + layerOff + jt * 16 + lane], racc[jt]);
            }
            gCur = -1;
#pragma unroll
            for (int jt = 0; jt < 8; ++jt) racc[jt] = 0.0f;
#pragma unroll
            for (int r = 0; r < 4; ++r) {
                const int i = i0 + lGrp * 4 + r;
                if (i < N) {
                    const int g = n2g[i];
#pragma unroll
                    for (int jt = 0; jt < 8; ++jt) {
                        float v = fmaxf(acc[jt][r], 0.0f) * scl[r];
                        unsafeAtomicAdd(&readout[(size_t)g * 384 + layerOff + jt * 16 + lRow], v);
                    }
                }
            }
        }
    }
    if (gCur >= 0 && lane < 16) {
#pragma unroll
        for (int jt = 0; jt < 8; ++jt)
            unsafeAtomicAdd(&readout[(size_t)gCur * 384 + layerOff + jt * 16 + lane], racc[jt]);
    }
}

// ---------------------------------------------------------------------------
extern "C" void kernel_launch(void* const* d_in, const int* in_sizes, int n_in,
                              void* d_out, int out_size, void* d_ws, size_t ws_size,
                              hipStream_t stream)
{
    const int*   gate_type = (const int*)d_in[0];
    const int*   src  = (const int*)d_in[1];
    const int*   dst  = (const int*)d_in[2];
    const float* wE   = (const float*)d_in[3];
    const int*   n2g  = (const int*)d_in[4];
    const float* emb  = (const float*)d_in[5];
    const float* W1_0 = (const float*)d_in[6];
    const float* b1_0 = (const float*)d_in[7];
    const float* W2_0 = (const float*)d_in[8];
    const float* W1_1 = (const float*)d_in[9];
    const float* b1_1 = (const float*)d_in[10];
    const float* W2_1 = (const float*)d_in[11];
    const float* W1_2 = (const float*)d_in[12];
    const float* b1_2 = (const float*)d_in[13];
    const float* W2_2 = (const float*)d_in[14];

    const int N = in_sizes[0];
    const int E = in_sizes[1];
    const int NGT = in_sizes[5] / 64;
    const int cap = (E + 3 * N + 15) & ~15;

    char* ws = (char*)d_ws;
    size_t off = 0;
    auto alloc = [&](size_t bytes) { void* p = ws + off; off = (off + bytes + 255) & ~255ULL; return p; };
    _Float16* hBuf  = (_Float16*)alloc((size_t)N * 128 * 2);
    int*      srcS  = (int*)alloc(((size_t)cap + 16) * 4);
    int*      dstS  = (int*)alloc(((size_t)cap + 16) * 4);
    half4*    wS4   = (half4*)alloc(((size_t)cap + 16) * 8);
    int*      cnt   = (int*)alloc((size_t)N * 4);
    int*      offP  = (int*)alloc((size_t)N * 4);
    int*      cur   = (int*)alloc((size_t)N * 4);
    int*      bSums = (int*)alloc(256 * 4);
    _Float16* W1T1  = (_Float16*)alloc((size_t)128 * 128 * 2);
    _Float16* W1T2  = (_Float16*)alloc((size_t)128 * 128 * 2);
    _Float16* W2T0  = (_Float16*)alloc((size_t)128 * 128 * 2);
    _Float16* W2T1  = (_Float16*)alloc((size_t)128 * 256 * 2);
    _Float16* W2T2  = (_Float16*)alloc((size_t)128 * 256 * 2);
    _Float16* eW1b  = (_Float16*)alloc((size_t)(NGT + 1) * 128 * 2);
    float*    eW2   = (float*)alloc((size_t)NGT * 128 * 4);
    _Float16* hW1b  = (_Float16*)alloc(((size_t)N + 1) * 128 * 2);  // per-node table
    size_t hn16_off = off;
    const bool h16 = (ws_size >= hn16_off + (size_t)N * 128 * 2 + 256);
    _Float16* hN16 = (_Float16*)alloc((size_t)N * 128 * 2);         // only if h16

    float* readout = (float*)d_out + (size_t)N * 128;  // [G,384]
    void*  hN      = h16 ? (void*)hN16 : (void*)d_out;

    const int nGroups = cap / 4;
    const int nTiles  = (N + 15) / 16;
    const int EB = 2048;                                 // edgeW blocks (4 waves)
    const int gpw = (nGroups + EB * 4 - 1) / (EB * 4);
    const int NB = 256;                                  // node/hw1 blocks (8 waves)
    const int tpwN = (nTiles + NB * 8 - 1) / (NB * 8);
    const int nb = (N + 1023) / 1024;

    // ---- init + counting sort (padded to 4 per dst) ----
    hipMemsetAsync(cnt, 0, (size_t)N * 4, stream);
    hipMemsetAsync(cur, 0, (size_t)N * 4, stream);
    hipMemsetAsync(wS4, 0, ((size_t)cap + 16) * 8, stream);
    hipMemsetAsync(hW1b + (size_t)N * 128, 0, 256, stream);   // zero pad row
    fill_dummy_kernel<<<(cap + 16 + 255) / 256, 256, 0, stream>>>(srcS, dstS, cap + 16, N, NGT);
    hist_kernel<<<(E + 255) / 256, 256, 0, stream>>>(dst, cnt, E);
    scan1p_kernel<<<nb, 256, 0, stream>>>(cnt, offP, N, bSums);
    scan2_kernel<<<1, 256, 0, stream>>>(bSums, nb);
    scan3_kernel<<<nb, 256, 0, stream>>>(offP, N, bSums);
    scatter_kernel<<<(E + 255) / 256, 256, 0, stream>>>(src, dst, wE, gate_type,
                                                        offP, cur, srcS, dstS, wS4, E);

    // ---- weight prep ----
    embW1_kernel<<<((NGT + 1) * 128 + 255) / 256, 256, 0, stream>>>(emb, W1_0, b1_0, eW1b, NGT);
    embW2_kernel<<<(NGT * 128 + 255) / 256, 256, 0, stream>>>(emb, W2_0, eW2, NGT);
    wprep_kernel<<<(128 * 128 + 255) / 256, 256, 0, stream>>>(W1_1, W1T1, 128, 128);
    wprep_kernel<<<(128 * 128 + 255) / 256, 256, 0, stream>>>(W1_2, W1T2, 128, 128);
    wprep_kernel<<<(128 * 128 + 255) / 256, 256, 0, stream>>>(W2_0 + (size_t)64 * 128, W2T0, 128, 128);
    wprep_kernel<<<(128 * 256 + 255) / 256, 256, 0, stream>>>(W2_1, W2T1, 256, 256);
    wprep_kernel<<<(128 * 256 + 255) / 256, 256, 0, stream>>>(W2_2, W2T2, 256, 256);

    if (h16) {
        hipMemsetAsync(readout, 0, (size_t)(out_size - N * 128) * 4, stream);
        hipMemsetAsync(hN16, 0, (size_t)N * 128 * 2, stream);
        // layer 0
        edgeW_kernel<true, true><<<EB, 256, 0, stream>>>(eW1b, W1_0 + (size_t)64 * 128,
                                                         srcS, dstS, wS4, hN, N, gpw, nGroups);
        node_kernel<true, true, false><<<NB, 512, 0, stream>>>(nullptr, hN, W2T0, eW2, gate_type, n2g,
                                                               hBuf, nullptr, readout, N, tpwN, nTiles, 0);
        // layer 1
        hw1_kernel<<<NB, 512, 0, stream>>>(hBuf, W1T1, b1_1, hW1b, N, tpwN, nTiles);
        hipMemsetAsync(hN16, 0, (size_t)N * 128 * 2, stream);
        edgeW_kernel<false, true><<<EB, 256, 0, stream>>>(hW1b, W1_1 + (size_t)128 * 128,
                                                          srcS, dstS, wS4, hN, N, gpw, nGroups);
        node_kernel<true, false, false><<<NB, 512, 0, stream>>>(hBuf, hN, W2T1, nullptr, nullptr, n2g,
                                                                hBuf, nullptr, readout, N, tpwN, nTiles, 128);
        // layer 2
        hw1_kernel<<<NB, 512, 0, stream>>>(hBuf, W1T2, b1_2, hW1b, N, tpwN, nTiles);
        hipMemsetAsync(hN16, 0, (size_t)N * 128 * 2, stream);
        edgeW_kernel<false, true><<<EB, 256, 0, stream>>>(hW1b, W1_2 + (size_t)128 * 128,
                                                          srcS, dstS, wS4, hN, N, gpw, nGroups);
        node_kernel<true, false, true><<<NB, 512, 0, stream>>>(hBuf, hN, W2T2, nullptr, nullptr, n2g,
                                                               nullptr, (float*)d_out, readout, N, tpwN, nTiles, 256);
    } else {
        hipMemsetAsync(d_out, 0, (size_t)out_size * 4, stream);
        // layer 0
        edgeW_kernel<true, false><<<EB, 256, 0, stream>>>(eW1b, W1_0 + (size_t)64 * 128,
                                                          srcS, dstS, wS4, hN, N, gpw, nGroups);
        node_kernel<false, true, false><<<NB, 512, 0, stream>>>(nullptr, hN, W2T0, eW2, gate_type, n2g,
                                                                hBuf, nullptr, readout, N, tpwN, nTiles, 0);
        // layer 1
        hw1_kernel<<<NB, 512, 0, stream>>>(hBuf, W1T1, b1_1, hW1b, N, tpwN, nTiles);
        hipMemsetAsync(d_out, 0, (size_t)N * 128 * 4, stream);
        edgeW_kernel<false, false><<<EB, 256, 0, stream>>>(hW1b, W1_1 + (size_t)128 * 128,
                                                           srcS, dstS, wS4, hN, N, gpw, nGroups);
        node_kernel<false, false, false><<<NB, 512, 0, stream>>>(hBuf, hN, W2T1, nullptr, nullptr, n2g,
                                                                 hBuf, nullptr, readout, N, tpwN, nTiles, 128);
        // layer 2
        hw1_kernel<<<NB, 512, 0, stream>>>(hBuf, W1T2, b1_2, hW1b, N, tpwN, nTiles);
        hipMemsetAsync(d_out, 0, (size_t)N * 128 * 4, stream);
        edgeW_kernel<false, false><<<EB, 256, 0, stream>>>(hW1b, W1_2 + (size_t)128 * 128,
                                                           srcS, dstS, wS4, hN, N, gpw, nGroups);
        node_kernel<false, false, true><<<NB, 512, 0, stream>>>(hBuf, hN, W2T2, nullptr, nullptr, n2g,
                                                                nullptr, (float*)d_out, readout, N, tpwN, nTiles, 256);
    }
}

// Round 9
// 625.066 us; speedup vs baseline: 1.8872x; 1.2109x over previous
//
#include <hip/hip_runtime.h>
#include <hip/hip_bf16.h>
#include <hip/hip_fp16.h>

typedef _Float16 half8 __attribute__((ext_vector_type(8)));
typedef _Float16 half4 __attribute__((ext_vector_type(4)));
typedef _Float16 h2    __attribute__((ext_vector_type(2)));
typedef float floatx4 __attribute__((ext_vector_type(4)));

__device__ __forceinline__ _Float16 f2h(float f) { return (_Float16)f; }

// ---------------------------------------------------------------------------
// dummy-fill padded edge arrays: src=N (zero row), g=NGT (zero emb row),
// dst=N (skip marker). wS4 zeroed by memset.
// ---------------------------------------------------------------------------
__global__ void fill_dummy_kernel(int* __restrict__ srcS, int* __restrict__ dstS,
                                  int cap, int N, int NGT)
{
    int i = blockIdx.x * 256 + threadIdx.x;
    if (i < cap) { srcS[i] = N | (NGT << 24); dstS[i] = N; }
}

__global__ void hist_kernel(const int* __restrict__ dst, int* __restrict__ cnt, int E)
{
    int e = blockIdx.x * 256 + threadIdx.x;
    if (e < E) atomicAdd(&cnt[dst[e]], 1);
}

// exclusive scan of per-node counts PADDED to multiple of 4 -> offP
__global__ void scan1p_kernel(const int* __restrict__ cnt, int* __restrict__ offP,
                              int n, int* __restrict__ blockSums)
{
    __shared__ int sm[256];
    const int t = threadIdx.x;
    const int base = blockIdx.x * 1024 + t * 4;
    int v[4]; int s = 0;
#pragma unroll
    for (int i = 0; i < 4; ++i) {
        v[i] = (base + i < n) ? ((cnt[base + i] + 3) & ~3) : 0;
        s += v[i];
    }
    sm[t] = s; __syncthreads();
#pragma unroll
    for (int off = 1; off < 256; off <<= 1) {
        int y = (t >= off) ? sm[t - off] : 0;
        __syncthreads();
        if (t >= off) sm[t] += y;
        __syncthreads();
    }
    int excl = sm[t] - s;
    if (t == 255) blockSums[blockIdx.x] = sm[255];
    int run = excl;
#pragma unroll
    for (int i = 0; i < 4; ++i) {
        if (base + i < n) offP[base + i] = run;
        run += v[i];
    }
}

__global__ void scan2_kernel(int* __restrict__ blockSums, int nb)
{
    __shared__ int sm[256];
    const int t = threadIdx.x;
    int s = (t < nb) ? blockSums[t] : 0;
    sm[t] = s; __syncthreads();
#pragma unroll
    for (int off = 1; off < 256; off <<= 1) {
        int y = (t >= off) ? sm[t - off] : 0;
        __syncthreads();
        if (t >= off) sm[t] += y;
        __syncthreads();
    }
    if (t < nb) blockSums[t] = sm[t] - s;
}

__global__ void scan3_kernel(int* __restrict__ offP, int n, const int* __restrict__ blockSums)
{
    const int base = blockIdx.x * 1024 + threadIdx.x * 4;
    const int add = blockSums[blockIdx.x];
#pragma unroll
    for (int i = 0; i < 4; ++i)
        if (base + i < n) offP[base + i] += add;
}

__global__ void scatter_kernel(const int* __restrict__ src, const int* __restrict__ dst,
                               const float* __restrict__ w, const int* __restrict__ gt,
                               const int* __restrict__ offP, int* __restrict__ cur,
                               int* __restrict__ srcS, int* __restrict__ dstS,
                               half4* __restrict__ wS4, int E)
{
    int e = blockIdx.x * 256 + threadIdx.x;
    if (e >= E) return;
    int d = dst[e];
    int p = offP[d] + atomicAdd(&cur[d], 1);
    int s = src[e];
    srcS[p] = s | (gt[s] << 24);
    dstS[p] = d;
    half4 q;
    q[0] = f2h(w[(size_t)e * 3 + 0]);
    q[1] = f2h(w[(size_t)e * 3 + 1]);
    q[2] = f2h(w[(size_t)e * 3 + 2]);
    q[3] = (_Float16)1.0f;
    wS4[p] = q;
}

// per-group info: dG (24b) | multi (bit31); dummy group = 0xFFFFFFFF
__global__ void ginfo_kernel(const int* __restrict__ dstS, unsigned* __restrict__ gInfo,
                             int nGroups, int N)
{
    int g = blockIdx.x * 256 + threadIdx.x;
    if (g >= nGroups) return;
    int d = dstS[4 * g];
    if (d >= N) { gInfo[g] = 0xFFFFFFFFu; return; }
    bool multi = (g > 0 && dstS[4 * g - 4] == d) || (dstS[4 * g + 4] == d);
    gInfo[g] = (unsigned)d | (multi ? 0x80000000u : 0u);
}

// ---------------------------------------------------------------------------
// weight prep: W [K,128] fp32 -> out [128,KP] f16 (outcol-major, k minor)
// ---------------------------------------------------------------------------
__global__ void wprep_kernel(const float* __restrict__ W, _Float16* __restrict__ out,
                             int K, int KP)
{
    int idx = blockIdx.x * 256 + threadIdx.x;
    if (idx >= 128 * KP) return;
    int f = idx / KP, k = idx % KP;
    float v = (k < K) ? W[(size_t)k * 128 + f] : 0.0f;
    out[idx] = f2h(v);
}

// w-rows of W1 -> f16 [3][128]
__global__ void wwprep_kernel(const float* __restrict__ W1, int rowOff,
                              _Float16* __restrict__ out)
{
    int idx = blockIdx.x * 256 + threadIdx.x;
    if (idx < 3 * 128) out[idx] = f2h(W1[(size_t)(rowOff + idx / 128) * 128 + (idx & 127)]);
}

// embW1b[g][f] = b1_0[f] + emb[g]@W1_0[:64] (f16); row NGT = zeros (pads)
__global__ void embW1_kernel(const float* __restrict__ emb, const float* __restrict__ W1,
                             const float* __restrict__ b1, _Float16* __restrict__ out, int NGT)
{
    int idx = blockIdx.x * 256 + threadIdx.x;
    if (idx >= (NGT + 1) * 128) return;
    int g = idx >> 7, f = idx & 127;
    float s = 0.0f;
    if (g < NGT) {
        s = b1[f];
        for (int k = 0; k < 64; ++k) s += emb[g * 64 + k] * W1[(size_t)k * 128 + f];
    }
    out[idx] = f2h(s);
}

__global__ void embW2_kernel(const float* __restrict__ emb, const float* __restrict__ W2,
                             float* __restrict__ out, int NGT)
{
    int idx = blockIdx.x * 256 + threadIdx.x;
    if (idx >= NGT * 128) return;
    int g = idx >> 7, f = idx & 127;
    float s = 0.0f;
    for (int k = 0; k < 64; ++k) s += emb[g * 64 + k] * W2[(size_t)k * 128 + f];
    out[idx] = s;
}

// ---------------------------------------------------------------------------
// hW1b = h @ W1[:128] + b1  (dense, per-node; feeds the edge kernel)
// ---------------------------------------------------------------------------
__global__ void __launch_bounds__(512, 2)
hw1_kernel(const _Float16* __restrict__ hA,   // [N,128]
           const _Float16* __restrict__ WT,   // [128 outcol, 128 k] f16
           const float* __restrict__ b1,
           _Float16* __restrict__ out,        // [(N+1),128]
           int N, int tilesPerWave, int nTiles)
{
    __shared__ __align__(16) _Float16 lds[128 * 128];
    const int tid = threadIdx.x;
    for (int s = tid; s < 128 * 16; s += 512) {
        const int row = s / 16, seg = s % 16;
        half8 v = *(const half8*)(WT + (size_t)row * 128 + seg * 8);
        *(half8*)(&lds[row * 128 + ((seg ^ (row & 7)) * 8)]) = v;
    }
    __syncthreads();

    const int lane = tid & 63;
    const int wv   = tid >> 6;
    const int lRow = lane & 15;
    const int lGrp = lane >> 4;

    float b1v[8];
#pragma unroll
    for (int jt = 0; jt < 8; ++jt) b1v[jt] = b1[jt * 16 + lRow];

    const int wave = blockIdx.x * 8 + wv;
    const int t0 = wave * tilesPerWave;
    const int t1 = min(t0 + tilesPerWave, nTiles);

    for (int tile = t0; tile < t1; ++tile) {
        const int i0 = tile * 16;
        const int iA = min(i0 + lRow, N - 1);
        half8 a[4];
#pragma unroll
        for (int kc = 0; kc < 4; ++kc)
            a[kc] = *(const half8*)(hA + (size_t)iA * 128 + kc * 32 + lGrp * 8);

        floatx4 acc[8] = {};
#pragma unroll
        for (int jt = 0; jt < 8; ++jt) {
            const int row = jt * 16 + lRow;
            const int sw = row & 7;
#pragma unroll
            for (int kc = 0; kc < 4; ++kc) {
                half8 b = *(const half8*)(&lds[row * 128 + (((kc * 4 + lGrp) ^ sw) * 8)]);
                acc[jt] = __builtin_amdgcn_mfma_f32_16x16x32_f16(a[kc], b, acc[jt], 0, 0, 0);
            }
        }
#pragma unroll
        for (int r = 0; r < 4; ++r) {
            const int i = i0 + lGrp * 4 + r;
            if (i < N) {
#pragma unroll
                for (int jt = 0; jt < 8; ++jt)
                    out[(size_t)i * 128 + jt * 16 + lRow] = f2h(acc[jt][r] + b1v[jt]);
            }
        }
    }
}

// ---------------------------------------------------------------------------
// edge kernel (ALL layers, no MFMA, packed f16 math via ext vectors):
//   per 4-edge group, t_e = relu(T[row(e)] + w_e @ Ww), hN[dst] = sum_e t_e
// ---------------------------------------------------------------------------
template<bool L0, bool H16>
__global__ void __launch_bounds__(256, 8)
edgeW_kernel(const _Float16* __restrict__ T,    // embW1b (L0) or hW1b
             const _Float16* __restrict__ Wwh,  // [3][128] f16
             const int* __restrict__ srcS,
             const half4* __restrict__ wS4,
             const unsigned* __restrict__ gInfo,
             void* __restrict__ hNv, int groupsPerWave, int nGroups)
{
    const int tid  = threadIdx.x;
    const int lane = tid & 63;
    const int wv   = tid >> 6;
    const int sub  = lane >> 5;          // 0/1: edge within pair
    const int col4 = (lane & 31) * 4;    // 4 consecutive output cols

    const h2 z = {(_Float16)0.0f, (_Float16)0.0f};
    const h2 w0a = *(const h2*)(Wwh + 0 * 128 + col4);
    const h2 w0b = *(const h2*)(Wwh + 0 * 128 + col4 + 2);
    const h2 w1a = *(const h2*)(Wwh + 1 * 128 + col4);
    const h2 w1b = *(const h2*)(Wwh + 1 * 128 + col4 + 2);
    const h2 w2a = *(const h2*)(Wwh + 2 * 128 + col4);
    const h2 w2b = *(const h2*)(Wwh + 2 * 128 + col4 + 2);

    const int wave = blockIdx.x * 4 + wv;
    const int g0 = wave * groupsPerWave;
    const int g1 = min(g0 + groupsPerWave, nGroups);

    auto doGroup = [&](int g) {
        const unsigned gi = gInfo[g];
        if (gi == 0xFFFFFFFFu) return;           // dummy tail group
        const int dG = (int)(gi & 0xFFFFFFu);
        const bool multi = (gi >> 31) != 0;
        const int eb = g * 4;
        const int sa = srcS[eb + sub];
        const int sb = srcS[eb + 2 + sub];
        const int ra = L0 ? (sa >> 24) : (sa & 0xFFFFFF);
        const int rb = L0 ? (sb >> 24) : (sb & 0xFFFFFF);
        const half4 qa = wS4[eb + sub];
        const half4 qb = wS4[eb + 2 + sub];
        const h2 Ta0 = *(const h2*)(T + (size_t)ra * 128 + col4);
        const h2 Ta1 = *(const h2*)(T + (size_t)ra * 128 + col4 + 2);
        const h2 Tb0 = *(const h2*)(T + (size_t)rb * 128 + col4);
        const h2 Tb1 = *(const h2*)(T + (size_t)rb * 128 + col4 + 2);

        h2 ma0 = Ta0 + qa[0] * w0a + qa[1] * w1a + qa[2] * w2a;
        h2 ma1 = Ta1 + qa[0] * w0b + qa[1] * w1b + qa[2] * w2b;
        h2 mb0 = Tb0 + qb[0] * w0a + qb[1] * w1a + qb[2] * w2a;
        h2 mb1 = Tb1 + qb[0] * w0b + qb[1] * w1b + qb[2] * w2b;
        h2 r0 = __builtin_elementwise_max(ma0, z) + __builtin_elementwise_max(mb0, z);
        h2 r1 = __builtin_elementwise_max(ma1, z) + __builtin_elementwise_max(mb1, z);
        int o0 = __shfl_xor(__builtin_bit_cast(int, r0), 32);
        int o1 = __shfl_xor(__builtin_bit_cast(int, r1), 32);
        r0 = r0 + __builtin_bit_cast(h2, o0);
        r1 = r1 + __builtin_bit_cast(h2, o1);

        if (lane < 32) {
            if (H16) {
                __half2 hr0 = __builtin_bit_cast(__half2, r0);
                __half2 hr1 = __builtin_bit_cast(__half2, r1);
                __half2* a0p = (__half2*)((__half*)hNv + (size_t)dG * 128 + col4);
                if (multi) { unsafeAtomicAdd(a0p, hr0); unsafeAtomicAdd(a0p + 1, hr1); }
                else       { a0p[0] = hr0; a0p[1] = hr1; }
            } else {
                float f0 = (float)r0[0], f1 = (float)r0[1];
                float f2 = (float)r1[0], f3 = (float)r1[1];
                float* a0p = (float*)hNv + (size_t)dG * 128 + col4;
                if (multi) {
                    unsafeAtomicAdd(a0p + 0, f0); unsafeAtomicAdd(a0p + 1, f1);
                    unsafeAtomicAdd(a0p + 2, f2); unsafeAtomicAdd(a0p + 3, f3);
                } else {
                    floatx4 p = {f0, f1, f2, f3};
                    *(floatx4*)a0p = p;
                }
            }
        }
    };

    int g = g0;
    for (; g + 1 < g1; g += 2) { doGroup(g); doGroup(g + 1); }
    if (g < g1) doGroup(g);
}

// ---------------------------------------------------------------------------
// node kernel (2-tile batched): h = normalize(relu([h,]hN @ W2 [+ embW2[gt]]))
// B-fragment read once per tile-pair -> halved LDS traffic.
// ---------------------------------------------------------------------------
template<bool H16, bool L0, bool LAST>
__global__ void __launch_bounds__(256, 2)
node_kernel(const _Float16* __restrict__ hA,    // [N,128] (unused if L0)
            const void* __restrict__ hNv,       // [N,128] f16 or f32
            const _Float16* __restrict__ W2T,   // [128,K2]
            const float* __restrict__ embW2,    // [30,128] (L0 only)
            const int* __restrict__ gt,         // (L0 only)
            const int* __restrict__ n2g,
            _Float16* __restrict__ hOut,        // if !LAST
            float* __restrict__ fOut,           // if LAST
            float* __restrict__ readout,
            int N, int tilesPerWave, int nTiles, int layerOff)
{
    constexpr int K2  = L0 ? 128 : 256;
    constexpr int KCA = L0 ? 0 : 4;
    constexpr int KC  = K2 / 32;
    constexpr int SPR = K2 / 8;
    __shared__ __align__(16) _Float16 lds[128 * K2];

    const int tid = threadIdx.x;
    for (int s = tid; s < 128 * SPR; s += 256) {
        const int row = s / SPR, seg = s % SPR;
        half8 v = *(const half8*)(W2T + (size_t)row * K2 + seg * 8);
        *(half8*)(&lds[row * K2 + ((seg ^ (row & 7)) * 8)]) = v;
    }
    __syncthreads();

    const int lane = tid & 63;
    const int wv   = tid >> 6;
    const int lRow = lane & 15;
    const int lGrp = lane >> 4;
    const int wave = blockIdx.x * 4 + wv;
    const int t0 = wave * tilesPerWave;
    const int t1 = min(t0 + tilesPerWave, nTiles);
    if (t0 >= t1) return;

    int gCur = -1; float racc[8];
#pragma unroll
    for (int jt = 0; jt < 8; ++jt) racc[jt] = 0.0f;

    auto loadA = [&](int i0, half8 (&afrag)[KC]) {
        const int iA = min(i0 + lRow, N - 1);
#pragma unroll
        for (int kc = 0; kc < KCA; ++kc)
            afrag[kc] = *(const half8*)(hA + (size_t)iA * 128 + kc * 32 + lGrp * 8);
        if (H16) {
            const _Float16* hN = (const _Float16*)hNv;
#pragma unroll
            for (int kc = KCA; kc < KC; ++kc)
                afrag[kc] = *(const half8*)(hN + (size_t)iA * 128 + (kc - KCA) * 32 + lGrp * 8);
        } else {
            const float* hN = (const float*)hNv;
#pragma unroll
            for (int kc = KCA; kc < KC; ++kc) {
                const float* p = hN + (size_t)iA * 128 + (kc - KCA) * 32 + lGrp * 8;
                floatx4 f0 = *(const floatx4*)(p);
                floatx4 f1 = *(const floatx4*)(p + 4);
                half8 a;
#pragma unroll
                for (int i = 0; i < 4; ++i) { a[i] = f2h(f0[i]); a[i + 4] = f2h(f1[i]); }
                afrag[kc] = a;
            }
        }
    };

    auto epilogue = [&](int i0, floatx4 (&acc)[8]) {
        if (L0) {
#pragma unroll
            for (int r = 0; r < 4; ++r) {
                const int i = min(i0 + lGrp * 4 + r, N - 1);
                const int g_t = gt[i];
#pragma unroll
                for (int jt = 0; jt < 8; ++jt)
                    acc[jt][r] += embW2[(size_t)g_t * 128 + jt * 16 + lRow];
            }
        }
        float scl[4];
#pragma unroll
        for (int r = 0; r < 4; ++r) {
            float s = 0.f;
#pragma unroll
            for (int jt = 0; jt < 8; ++jt) {
                float v = fmaxf(acc[jt][r], 0.0f);
                s += v * v;
            }
#pragma unroll
            for (int m = 1; m <= 8; m <<= 1) s += __shfl_xor(s, m);
            scl[r] = 1.0f / fmaxf(sqrtf(s), 1e-12f);
        }
#pragma unroll
        for (int r = 0; r < 4; ++r) {
            const int i = i0 + lGrp * 4 + r;
            if (i < N) {
#pragma unroll
                for (int jt = 0; jt < 8; ++jt) {
                    float v = fmaxf(acc[jt][r], 0.0f) * scl[r];
                    if (LAST) fOut[(size_t)i * 128 + jt * 16 + lRow] = v;
                    else      hOut[(size_t)i * 128 + jt * 16 + lRow] = f2h(v);
                }
            }
        }
        const int gFirst = n2g[min(i0, N - 1)];
        const int gLast  = n2g[min(i0 + 15, N - 1)];
        if (gFirst == gLast && i0 + 15 < N) {
            if (gFirst != gCur) {
                if (gCur >= 0 && lane < 16) {
#pragma unroll
                    for (int jt = 0; jt < 8; ++jt)
                        unsafeAtomicAdd(&readout[(size_t)gCur * 384 + layerOff + jt * 16 + lane], racc[jt]);
                }
                gCur = gFirst;
#pragma unroll
                for (int jt = 0; jt < 8; ++jt) racc[jt] = 0.0f;
            }
#pragma unroll
            for (int jt = 0; jt < 8; ++jt) {
                float t = 0.f;
#pragma unroll
                for (int r = 0; r < 4; ++r) t += fmaxf(acc[jt][r], 0.0f) * scl[r];
                t += __shfl_xor(t, 16);
                t += __shfl_xor(t, 32);
                racc[jt] += t;
            }
        } else {
            if (gCur >= 0 && lane < 16) {
#pragma unroll
                for (int jt = 0; jt < 8; ++jt)
                    unsafeAtomicAdd(&readout[(size_t)gCur * 384 + layerOff + jt * 16 + lane], racc[jt]);
            }
            gCur = -1;
#pragma unroll
            for (int jt = 0; jt < 8; ++jt) racc[jt] = 0.0f;
#pragma unroll
            for (int r = 0; r < 4; ++r) {
                const int i = i0 + lGrp * 4 + r;
                if (i < N) {
                    const int g = n2g[i];
#pragma unroll
                    for (int jt = 0; jt < 8; ++jt) {
                        float v = fmaxf(acc[jt][r], 0.0f) * scl[r];
                        unsafeAtomicAdd(&readout[(size_t)g * 384 + layerOff + jt * 16 + lRow], v);
                    }
                }
            }
        }
    };

    for (int tile = t0; tile < t1; tile += 2) {
        const bool has2 = (tile + 1 < t1);
        const int i0a = tile * 16;
        const int i0b = has2 ? (tile + 1) * 16 : i0a;

        half8 afA[KC], afB[KC];
        loadA(i0a, afA);
        loadA(i0b, afB);

        floatx4 accA[8] = {}, accB[8] = {};
#pragma unroll
        for (int jt = 0; jt < 8; ++jt) {
            const int rb = (jt * 16 + lRow) * K2;
            const int sw = (jt * 16 + lRow) & 7;
#pragma unroll
            for (int kc = 0; kc < KC; ++kc) {
                half8 b = *(const half8*)(&lds[rb + (((kc * 4 + lGrp) ^ sw) * 8)]);
                accA[jt] = __builtin_amdgcn_mfma_f32_16x16x32_f16(afA[kc], b, accA[jt], 0, 0, 0);
                accB[jt] = __builtin_amdgcn_mfma_f32_16x16x32_f16(afB[kc], b, accB[jt], 0, 0, 0);
            }
        }
        epilogue(i0a, accA);
        if (has2) epilogue(i0b, accB);
    }
    if (gCur >= 0 && lane < 16) {
#pragma unroll
        for (int jt = 0; jt < 8; ++jt)
            unsafeAtomicAdd(&readout[(size_t)gCur * 384 + layerOff + jt * 16 + lane], racc[jt]);
    }
}

// ---------------------------------------------------------------------------
extern "C" void kernel_launch(void* const* d_in, const int* in_sizes, int n_in,
                              void* d_out, int out_size, void* d_ws, size_t ws_size,
                              hipStream_t stream)
{
    const int*   gate_type = (const int*)d_in[0];
    const int*   src  = (const int*)d_in[1];
    const int*   dst  = (const int*)d_in[2];
    const float* wE   = (const float*)d_in[3];
    const int*   n2g  = (const int*)d_in[4];
    const float* emb  = (const float*)d_in[5];
    const float* W1_0 = (const float*)d_in[6];
    const float* b1_0 = (const float*)d_in[7];
    const float* W2_0 = (const float*)d_in[8];
    const float* W1_1 = (const float*)d_in[9];
    const float* b1_1 = (const float*)d_in[10];
    const float* W2_1 = (const float*)d_in[11];
    const float* W1_2 = (const float*)d_in[12];
    const float* b1_2 = (const float*)d_in[13];
    const float* W2_2 = (const float*)d_in[14];

    const int N = in_sizes[0];
    const int E = in_sizes[1];
    const int NGT = in_sizes[5] / 64;
    const int cap = (E + 3 * N + 15) & ~15;

    char* ws = (char*)d_ws;
    size_t off = 0;
    auto alloc = [&](size_t bytes) { void* p = ws + off; off = (off + bytes + 255) & ~255ULL; return p; };
    _Float16* hBuf  = (_Float16*)alloc((size_t)N * 128 * 2);
    int*      srcS  = (int*)alloc(((size_t)cap + 16) * 4);
    int*      dstS  = (int*)alloc(((size_t)cap + 16) * 4);
    half4*    wS4   = (half4*)alloc(((size_t)cap + 16) * 8);
    unsigned* gInfo = (unsigned*)alloc(((size_t)cap / 4 + 4) * 4);
    int*      cnt   = (int*)alloc((size_t)N * 4);
    int*      offP  = (int*)alloc((size_t)N * 4);
    int*      cur   = (int*)alloc((size_t)N * 4);
    int*      bSums = (int*)alloc(256 * 4);
    _Float16* W1T1  = (_Float16*)alloc((size_t)128 * 128 * 2);
    _Float16* W1T2  = (_Float16*)alloc((size_t)128 * 128 * 2);
    _Float16* W2T0  = (_Float16*)alloc((size_t)128 * 128 * 2);
    _Float16* W2T1  = (_Float16*)alloc((size_t)128 * 256 * 2);
    _Float16* W2T2  = (_Float16*)alloc((size_t)128 * 256 * 2);
    _Float16* Wwh0  = (_Float16*)alloc((size_t)3 * 128 * 2);
    _Float16* Wwh1  = (_Float16*)alloc((size_t)3 * 128 * 2);
    _Float16* Wwh2  = (_Float16*)alloc((size_t)3 * 128 * 2);
    _Float16* eW1b  = (_Float16*)alloc((size_t)(NGT + 1) * 128 * 2);
    float*    eW2   = (float*)alloc((size_t)NGT * 128 * 4);
    _Float16* hW1b  = (_Float16*)alloc(((size_t)N + 1) * 128 * 2);
    size_t hn16_off = off;
    const bool h16 = (ws_size >= hn16_off + (size_t)N * 128 * 2 + 256);
    _Float16* hN16 = (_Float16*)alloc((size_t)N * 128 * 2);

    float* readout = (float*)d_out + (size_t)N * 128;  // [G,384]
    void*  hN      = h16 ? (void*)hN16 : (void*)d_out;

    const int nGroups = cap / 4;
    const int nTiles  = (N + 15) / 16;
    const int EB = 2048;                                 // edgeW blocks (4 waves)
    const int gpw = (nGroups + EB * 4 - 1) / (EB * 4);
    const int NB = 512;                                  // node blocks (4 waves)
    const int tpwN = (nTiles + NB * 4 - 1) / (NB * 4);
    const int HB = 256;                                  // hw1 blocks (8 waves)
    const int tpwH = (nTiles + HB * 8 - 1) / (HB * 8);
    const int nb = (N + 1023) / 1024;

    // ---- init + counting sort (padded to 4 per dst) ----
    hipMemsetAsync(cnt, 0, (size_t)N * 4, stream);
    hipMemsetAsync(cur, 0, (size_t)N * 4, stream);
    hipMemsetAsync(wS4, 0, ((size_t)cap + 16) * 8, stream);
    hipMemsetAsync(hW1b + (size_t)N * 128, 0, 256, stream);   // zero pad row
    fill_dummy_kernel<<<(cap + 16 + 255) / 256, 256, 0, stream>>>(srcS, dstS, cap + 16, N, NGT);
    hist_kernel<<<(E + 255) / 256, 256, 0, stream>>>(dst, cnt, E);
    scan1p_kernel<<<nb, 256, 0, stream>>>(cnt, offP, N, bSums);
    scan2_kernel<<<1, 256, 0, stream>>>(bSums, nb);
    scan3_kernel<<<nb, 256, 0, stream>>>(offP, N, bSums);
    scatter_kernel<<<(E + 255) / 256, 256, 0, stream>>>(src, dst, wE, gate_type,
                                                        offP, cur, srcS, dstS, wS4, E);
    ginfo_kernel<<<(nGroups + 255) / 256, 256, 0, stream>>>(dstS, gInfo, nGroups, N);

    // ---- weight prep ----
    embW1_kernel<<<((NGT + 1) * 128 + 255) / 256, 256, 0, stream>>>(emb, W1_0, b1_0, eW1b, NGT);
    embW2_kernel<<<(NGT * 128 + 255) / 256, 256, 0, stream>>>(emb, W2_0, eW2, NGT);
    wprep_kernel<<<(128 * 128 + 255) / 256, 256, 0, stream>>>(W1_1, W1T1, 128, 128);
    wprep_kernel<<<(128 * 128 + 255) / 256, 256, 0, stream>>>(W1_2, W1T2, 128, 128);
    wprep_kernel<<<(128 * 128 + 255) / 256, 256, 0, stream>>>(W2_0 + (size_t)64 * 128, W2T0, 128, 128);
    wprep_kernel<<<(128 * 256 + 255) / 256, 256, 0, stream>>>(W2_1, W2T1, 256, 256);
    wprep_kernel<<<(128 * 256 + 255) / 256, 256, 0, stream>>>(W2_2, W2T2, 256, 256);
    wwprep_kernel<<<2, 256, 0, stream>>>(W1_0, 64, Wwh0);
    wwprep_kernel<<<2, 256, 0, stream>>>(W1_1, 128, Wwh1);
    wwprep_kernel<<<2, 256, 0, stream>>>(W1_2, 128, Wwh2);

    if (h16) {
        hipMemsetAsync(readout, 0, (size_t)(out_size - N * 128) * 4, stream);
        hipMemsetAsync(hN16, 0, (size_t)N * 128 * 2, stream);
        // layer 0
        edgeW_kernel<true, true><<<EB, 256, 0, stream>>>(eW1b, Wwh0, srcS, wS4, gInfo, hN, gpw, nGroups);
        node_kernel<true, true, false><<<NB, 256, 0, stream>>>(nullptr, hN, W2T0, eW2, gate_type, n2g,
                                                               hBuf, nullptr, readout, N, tpwN, nTiles, 0);
        // layer 1
        hw1_kernel<<<HB, 512, 0, stream>>>(hBuf, W1T1, b1_1, hW1b, N, tpwH, nTiles);
        hipMemsetAsync(hN16, 0, (size_t)N * 128 * 2, stream);
        edgeW_kernel<false, true><<<EB, 256, 0, stream>>>(hW1b, Wwh1, srcS, wS4, gInfo, hN, gpw, nGroups);
        node_kernel<true, false, false><<<NB, 256, 0, stream>>>(hBuf, hN, W2T1, nullptr, nullptr, n2g,
                                                                hBuf, nullptr, readout, N, tpwN, nTiles, 128);
        // layer 2
        hw1_kernel<<<HB, 512, 0, stream>>>(hBuf, W1T2, b1_2, hW1b, N, tpwH, nTiles);
        hipMemsetAsync(hN16, 0, (size_t)N * 128 * 2, stream);
        edgeW_kernel<false, true><<<EB, 256, 0, stream>>>(hW1b, Wwh2, srcS, wS4, gInfo, hN, gpw, nGroups);
        node_kernel<true, false, true><<<NB, 256, 0, stream>>>(hBuf, hN, W2T2, nullptr, nullptr, n2g,
                                                               nullptr, (float*)d_out, readout, N, tpwN, nTiles, 256);
    } else {
        hipMemsetAsync(d_out, 0, (size_t)out_size * 4, stream);
        // layer 0
        edgeW_kernel<true, false><<<EB, 256, 0, stream>>>(eW1b, Wwh0, srcS, wS4, gInfo, hN, gpw, nGroups);
        node_kernel<false, true, false><<<NB, 256, 0, stream>>>(nullptr, hN, W2T0, eW2, gate_type, n2g,
                                                                hBuf, nullptr, readout, N, tpwN, nTiles, 0);
        // layer 1
        hw1_kernel<<<HB, 512, 0, stream>>>(hBuf, W1T1, b1_1, hW1b, N, tpwH, nTiles);
        hipMemsetAsync(d_out, 0, (size_t)N * 128 * 4, stream);
        edgeW_kernel<false, false><<<EB, 256, 0, stream>>>(hW1b, Wwh1, srcS, wS4, gInfo, hN, gpw, nGroups);
        node_kernel<false, false, false><<<NB, 256, 0, stream>>>(hBuf, hN, W2T1, nullptr, nullptr, n2g,
                                                                 hBuf, nullptr, readout, N, tpwN, nTiles, 128);
        // layer 2
        hw1_kernel<<<HB, 512, 0, stream>>>(hBuf, W1T2, b1_2, hW1b, N, tpwH, nTiles);
        hipMemsetAsync(d_out, 0, (size_t)N * 128 * 4, stream);
        edgeW_kernel<false, false><<<EB, 256, 0, stream>>>(hW1b, Wwh2, srcS, wS4, gInfo, hN, gpw, nGroups);
        node_kernel<false, false, true><<<NB, 256, 0, stream>>>(hBuf, hN, W2T2, nullptr, nullptr, n2g,
                                                                nullptr, (float*)d_out, readout, N, tpwN, nTiles, 256);
    }
}

// Round 10
// 589.606 us; speedup vs baseline: 2.0007x; 1.0601x over previous
//
#include <hip/hip_runtime.h>
#include <hip/hip_bf16.h>
#include <hip/hip_fp16.h>

typedef _Float16 half8 __attribute__((ext_vector_type(8)));
typedef _Float16 half4 __attribute__((ext_vector_type(4)));
typedef _Float16 h2    __attribute__((ext_vector_type(2)));
typedef float floatx4 __attribute__((ext_vector_type(4)));

__device__ __forceinline__ _Float16 f2h(float f) { return (_Float16)f; }

// eData slot (16B): {src | gt<<24, dst, w01 (2xf16), w2_one (2xf16)}
// dummy slot: {N | NGT<<24, N, 0, 0}

// ---------------------------------------------------------------------------
__global__ void fill_dummy_kernel(int4* __restrict__ eData, int cap, int N, int NGT)
{
    int i = blockIdx.x * 256 + threadIdx.x;
    if (i < cap) { int4 v = {N | (NGT << 24), N, 0, 0}; eData[i] = v; }
}

__global__ void hist_kernel(const int* __restrict__ dst, int* __restrict__ cnt, int E)
{
    int e = blockIdx.x * 256 + threadIdx.x;
    if (e < E) atomicAdd(&cnt[dst[e]], 1);
}

// exclusive scan of per-node counts PADDED to multiple of 4 -> offP
__global__ void scan1p_kernel(const int* __restrict__ cnt, int* __restrict__ offP,
                              int n, int* __restrict__ blockSums)
{
    __shared__ int sm[256];
    const int t = threadIdx.x;
    const int base = blockIdx.x * 1024 + t * 4;
    int v[4]; int s = 0;
#pragma unroll
    for (int i = 0; i < 4; ++i) {
        v[i] = (base + i < n) ? ((cnt[base + i] + 3) & ~3) : 0;
        s += v[i];
    }
    sm[t] = s; __syncthreads();
#pragma unroll
    for (int off = 1; off < 256; off <<= 1) {
        int y = (t >= off) ? sm[t - off] : 0;
        __syncthreads();
        if (t >= off) sm[t] += y;
        __syncthreads();
    }
    int excl = sm[t] - s;
    if (t == 255) blockSums[blockIdx.x] = sm[255];
    int run = excl;
#pragma unroll
    for (int i = 0; i < 4; ++i) {
        if (base + i < n) offP[base + i] = run;
        run += v[i];
    }
}

__global__ void scan2_kernel(int* __restrict__ blockSums, int nb)
{
    __shared__ int sm[256];
    const int t = threadIdx.x;
    int s = (t < nb) ? blockSums[t] : 0;
    sm[t] = s; __syncthreads();
#pragma unroll
    for (int off = 1; off < 256; off <<= 1) {
        int y = (t >= off) ? sm[t - off] : 0;
        __syncthreads();
        if (t >= off) sm[t] += y;
        __syncthreads();
    }
    if (t < nb) blockSums[t] = sm[t] - s;
}

__global__ void scan3_kernel(int* __restrict__ offP, int n, const int* __restrict__ blockSums)
{
    const int base = blockIdx.x * 1024 + threadIdx.x * 4;
    const int add = blockSums[blockIdx.x];
#pragma unroll
    for (int i = 0; i < 4; ++i)
        if (base + i < n) offP[base + i] += add;
}

// single 16B store per edge into the sorted slot
__global__ void scatter_kernel(const int* __restrict__ src, const int* __restrict__ dst,
                               const float* __restrict__ w, const int* __restrict__ gt,
                               const int* __restrict__ offP, int* __restrict__ cur,
                               int4* __restrict__ eData, int E)
{
    int e = blockIdx.x * 256 + threadIdx.x;
    if (e >= E) return;
    int d = dst[e];
    int p = offP[d] + atomicAdd(&cur[d], 1);
    int s = src[e];
    h2 w01 = { f2h(w[(size_t)e * 3 + 0]), f2h(w[(size_t)e * 3 + 1]) };
    h2 w2o = { f2h(w[(size_t)e * 3 + 2]), (_Float16)1.0f };
    int4 v = { s | (gt[s] << 24), d,
               __builtin_bit_cast(int, w01), __builtin_bit_cast(int, w2o) };
    eData[p] = v;
}

// per-group info: dG (24b) | multi (bit31); dummy group = 0xFFFFFFFF
__global__ void ginfo_kernel(const int4* __restrict__ eData, unsigned* __restrict__ gInfo,
                             int nGroups, int N)
{
    int g = blockIdx.x * 256 + threadIdx.x;
    if (g >= nGroups) return;
    const int* ei = (const int*)eData;
    int d = ei[16 * g + 1];
    if (d >= N) { gInfo[g] = 0xFFFFFFFFu; return; }
    bool multi = (g > 0 && ei[16 * (g - 1) + 1] == d) || (ei[16 * (g + 1) + 1] == d);
    gInfo[g] = (unsigned)d | (multi ? 0x80000000u : 0u);
}

// ---------------------------------------------------------------------------
// weight prep: W [K,128] fp32 -> out [128,KP] f16 (outcol-major, k minor)
// ---------------------------------------------------------------------------
__global__ void wprep_kernel(const float* __restrict__ W, _Float16* __restrict__ out,
                             int K, int KP)
{
    int idx = blockIdx.x * 256 + threadIdx.x;
    if (idx >= 128 * KP) return;
    int f = idx / KP, k = idx % KP;
    float v = (k < K) ? W[(size_t)k * 128 + f] : 0.0f;
    out[idx] = f2h(v);
}

// w-rows of W1 -> f16 [3][128]
__global__ void wwprep_kernel(const float* __restrict__ W1, int rowOff,
                              _Float16* __restrict__ out)
{
    int idx = blockIdx.x * 256 + threadIdx.x;
    if (idx < 3 * 128) out[idx] = f2h(W1[(size_t)(rowOff + idx / 128) * 128 + (idx & 127)]);
}

// embW1b[g][f] = b1_0[f] + emb[g]@W1_0[:64] (f16); row NGT = zeros (pads)
__global__ void embW1_kernel(const float* __restrict__ emb, const float* __restrict__ W1,
                             const float* __restrict__ b1, _Float16* __restrict__ out, int NGT)
{
    int idx = blockIdx.x * 256 + threadIdx.x;
    if (idx >= (NGT + 1) * 128) return;
    int g = idx >> 7, f = idx & 127;
    float s = 0.0f;
    if (g < NGT) {
        s = b1[f];
        for (int k = 0; k < 64; ++k) s += emb[g * 64 + k] * W1[(size_t)k * 128 + f];
    }
    out[idx] = f2h(s);
}

__global__ void embW2_kernel(const float* __restrict__ emb, const float* __restrict__ W2,
                             float* __restrict__ out, int NGT)
{
    int idx = blockIdx.x * 256 + threadIdx.x;
    if (idx >= NGT * 128) return;
    int g = idx >> 7, f = idx & 127;
    float s = 0.0f;
    for (int k = 0; k < 64; ++k) s += emb[g * 64 + k] * W2[(size_t)k * 128 + f];
    out[idx] = s;
}

// ---------------------------------------------------------------------------
// hW1b = h @ W1[:128] + b1  (dense, per-node; feeds the edge kernel)
// ---------------------------------------------------------------------------
__global__ void __launch_bounds__(512, 2)
hw1_kernel(const _Float16* __restrict__ hA,   // [N,128]
           const _Float16* __restrict__ WT,   // [128 outcol, 128 k] f16
           const float* __restrict__ b1,
           _Float16* __restrict__ out,        // [(N+1),128]
           int N, int tilesPerWave, int nTiles)
{
    __shared__ __align__(16) _Float16 lds[128 * 128];
    const int tid = threadIdx.x;
    for (int s = tid; s < 128 * 16; s += 512) {
        const int row = s / 16, seg = s % 16;
        half8 v = *(const half8*)(WT + (size_t)row * 128 + seg * 8);
        *(half8*)(&lds[row * 128 + ((seg ^ (row & 7)) * 8)]) = v;
    }
    __syncthreads();

    const int lane = tid & 63;
    const int wv   = tid >> 6;
    const int lRow = lane & 15;
    const int lGrp = lane >> 4;

    float b1v[8];
#pragma unroll
    for (int jt = 0; jt < 8; ++jt) b1v[jt] = b1[jt * 16 + lRow];

    const int wave = blockIdx.x * 8 + wv;
    const int t0 = wave * tilesPerWave;
    const int t1 = min(t0 + tilesPerWave, nTiles);

    for (int tile = t0; tile < t1; ++tile) {
        const int i0 = tile * 16;
        const int iA = min(i0 + lRow, N - 1);
        half8 a[4];
#pragma unroll
        for (int kc = 0; kc < 4; ++kc)
            a[kc] = *(const half8*)(hA + (size_t)iA * 128 + kc * 32 + lGrp * 8);

        floatx4 acc[8] = {};
#pragma unroll
        for (int jt = 0; jt < 8; ++jt) {
            const int row = jt * 16 + lRow;
            const int sw = row & 7;
#pragma unroll
            for (int kc = 0; kc < 4; ++kc) {
                half8 b = *(const half8*)(&lds[row * 128 + (((kc * 4 + lGrp) ^ sw) * 8)]);
                acc[jt] = __builtin_amdgcn_mfma_f32_16x16x32_f16(a[kc], b, acc[jt], 0, 0, 0);
            }
        }
#pragma unroll
        for (int r = 0; r < 4; ++r) {
            const int i = i0 + lGrp * 4 + r;
            if (i < N) {
#pragma unroll
                for (int jt = 0; jt < 8; ++jt)
                    out[(size_t)i * 128 + jt * 16 + lRow] = f2h(acc[jt][r] + b1v[jt]);
            }
        }
    }
}

// ---------------------------------------------------------------------------
// edge kernel (ALL layers, no MFMA, packed f16 math via ext vectors):
//   per 4-edge group, t_e = relu(T[row(e)] + w_e @ Ww), hN[dst] = sum_e t_e
// ---------------------------------------------------------------------------
template<bool L0, bool H16>
__global__ void __launch_bounds__(256, 8)
edgeW_kernel(const _Float16* __restrict__ T,    // embW1b (L0) or hW1b
             const _Float16* __restrict__ Wwh,  // [3][128] f16
             const int4* __restrict__ eData,
             const unsigned* __restrict__ gInfo,
             void* __restrict__ hNv, int groupsPerWave, int nGroups)
{
    const int tid  = threadIdx.x;
    const int lane = tid & 63;
    const int wv   = tid >> 6;
    const int sub  = lane >> 5;          // 0/1: edge within pair
    const int col4 = (lane & 31) * 4;    // 4 consecutive output cols

    const h2 z = {(_Float16)0.0f, (_Float16)0.0f};
    const h2 w0a = *(const h2*)(Wwh + 0 * 128 + col4);
    const h2 w0b = *(const h2*)(Wwh + 0 * 128 + col4 + 2);
    const h2 w1a = *(const h2*)(Wwh + 1 * 128 + col4);
    const h2 w1b = *(const h2*)(Wwh + 1 * 128 + col4 + 2);
    const h2 w2a = *(const h2*)(Wwh + 2 * 128 + col4);
    const h2 w2b = *(const h2*)(Wwh + 2 * 128 + col4 + 2);

    const int wave = blockIdx.x * 4 + wv;
    const int g0 = wave * groupsPerWave;
    const int g1 = min(g0 + groupsPerWave, nGroups);

    auto doGroup = [&](int g) {
        const unsigned gi = gInfo[g];
        if (gi == 0xFFFFFFFFu) return;           // dummy tail group
        const int dG = (int)(gi & 0xFFFFFFu);
        const bool multi = (gi >> 31) != 0;
        const int eb = g * 4;
        const int4 ea = eData[eb + sub];
        const int4 eb2 = eData[eb + 2 + sub];
        const int ra = L0 ? (ea.x >> 24) : (ea.x & 0xFFFFFF);
        const int rb = L0 ? (eb2.x >> 24) : (eb2.x & 0xFFFFFF);
        const h2 wa01 = __builtin_bit_cast(h2, ea.z);
        const h2 wa2o = __builtin_bit_cast(h2, ea.w);
        const h2 wb01 = __builtin_bit_cast(h2, eb2.z);
        const h2 wb2o = __builtin_bit_cast(h2, eb2.w);
        const half4 Tav = *(const half4*)(T + (size_t)ra * 128 + col4);
        const half4 Tbv = *(const half4*)(T + (size_t)rb * 128 + col4);
        const h2 Ta0 = {Tav[0], Tav[1]}, Ta1 = {Tav[2], Tav[3]};
        const h2 Tb0 = {Tbv[0], Tbv[1]}, Tb1 = {Tbv[2], Tbv[3]};

        h2 ma0 = Ta0 + wa01[0] * w0a + wa01[1] * w1a + wa2o[0] * w2a;
        h2 ma1 = Ta1 + wa01[0] * w0b + wa01[1] * w1b + wa2o[0] * w2b;
        h2 mb0 = Tb0 + wb01[0] * w0a + wb01[1] * w1a + wb2o[0] * w2a;
        h2 mb1 = Tb1 + wb01[0] * w0b + wb01[1] * w1b + wb2o[0] * w2b;
        h2 r0 = __builtin_elementwise_max(ma0, z) + __builtin_elementwise_max(mb0, z);
        h2 r1 = __builtin_elementwise_max(ma1, z) + __builtin_elementwise_max(mb1, z);
        int o0 = __shfl_xor(__builtin_bit_cast(int, r0), 32);
        int o1 = __shfl_xor(__builtin_bit_cast(int, r1), 32);
        r0 = r0 + __builtin_bit_cast(h2, o0);
        r1 = r1 + __builtin_bit_cast(h2, o1);

        if (lane < 32) {
            if (H16) {
                if (multi) {
                    __half2* a0p = (__half2*)((__half*)hNv + (size_t)dG * 128 + col4);
                    unsafeAtomicAdd(a0p, __builtin_bit_cast(__half2, r0));
                    unsafeAtomicAdd(a0p + 1, __builtin_bit_cast(__half2, r1));
                } else {
                    int2 pk = { __builtin_bit_cast(int, r0), __builtin_bit_cast(int, r1) };
                    *(int2*)((__half*)hNv + (size_t)dG * 128 + col4) = pk;
                }
            } else {
                float f0 = (float)r0[0], f1 = (float)r0[1];
                float f2 = (float)r1[0], f3 = (float)r1[1];
                float* a0p = (float*)hNv + (size_t)dG * 128 + col4;
                if (multi) {
                    unsafeAtomicAdd(a0p + 0, f0); unsafeAtomicAdd(a0p + 1, f1);
                    unsafeAtomicAdd(a0p + 2, f2); unsafeAtomicAdd(a0p + 3, f3);
                } else {
                    floatx4 p = {f0, f1, f2, f3};
                    *(floatx4*)a0p = p;
                }
            }
        }
    };

    int g = g0;
    for (; g + 1 < g1; g += 2) { doGroup(g); doGroup(g + 1); }
    if (g < g1) doGroup(g);
}

// ---------------------------------------------------------------------------
// node kernel (2-tile batched): h = normalize(relu([h,]hN @ W2 [+ embW2[gt]]))
// ---------------------------------------------------------------------------
template<bool H16, bool L0, bool LAST>
__global__ void __launch_bounds__(256, 2)
node_kernel(const _Float16* __restrict__ hA,    // [N,128] (unused if L0)
            const void* __restrict__ hNv,       // [N,128] f16 or f32
            const _Float16* __restrict__ W2T,   // [128,K2]
            const float* __restrict__ embW2,    // [30,128] (L0 only)
            const int* __restrict__ gt,         // (L0 only)
            const int* __restrict__ n2g,
            _Float16* __restrict__ hOut,        // if !LAST
            float* __restrict__ fOut,           // if LAST
            float* __restrict__ readout,
            int N, int tilesPerWave, int nTiles, int layerOff)
{
    constexpr int K2  = L0 ? 128 : 256;
    constexpr int KCA = L0 ? 0 : 4;
    constexpr int KC  = K2 / 32;
    constexpr int SPR = K2 / 8;
    __shared__ __align__(16) _Float16 lds[128 * K2];

    const int tid = threadIdx.x;
    for (int s = tid; s < 128 * SPR; s += 256) {
        const int row = s / SPR, seg = s % SPR;
        half8 v = *(const half8*)(W2T + (size_t)row * K2 + seg * 8);
        *(half8*)(&lds[row * K2 + ((seg ^ (row & 7)) * 8)]) = v;
    }
    __syncthreads();

    const int lane = tid & 63;
    const int wv   = tid >> 6;
    const int lRow = lane & 15;
    const int lGrp = lane >> 4;
    const int wave = blockIdx.x * 4 + wv;
    const int t0 = wave * tilesPerWave;
    const int t1 = min(t0 + tilesPerWave, nTiles);
    if (t0 >= t1) return;

    int gCur = -1; float racc[8];
#pragma unroll
    for (int jt = 0; jt < 8; ++jt) racc[jt] = 0.0f;

    auto loadA = [&](int i0, half8 (&afrag)[KC]) {
        const int iA = min(i0 + lRow, N - 1);
#pragma unroll
        for (int kc = 0; kc < KCA; ++kc)
            afrag[kc] = *(const half8*)(hA + (size_t)iA * 128 + kc * 32 + lGrp * 8);
        if (H16) {
            const _Float16* hN = (const _Float16*)hNv;
#pragma unroll
            for (int kc = KCA; kc < KC; ++kc)
                afrag[kc] = *(const half8*)(hN + (size_t)iA * 128 + (kc - KCA) * 32 + lGrp * 8);
        } else {
            const float* hN = (const float*)hNv;
#pragma unroll
            for (int kc = KCA; kc < KC; ++kc) {
                const float* p = hN + (size_t)iA * 128 + (kc - KCA) * 32 + lGrp * 8;
                floatx4 f0 = *(const floatx4*)(p);
                floatx4 f1 = *(const floatx4*)(p + 4);
                half8 a;
#pragma unroll
                for (int i = 0; i < 4; ++i) { a[i] = f2h(f0[i]); a[i + 4] = f2h(f1[i]); }
                afrag[kc] = a;
            }
        }
    };

    auto epilogue = [&](int i0, floatx4 (&acc)[8]) {
        if (L0) {
#pragma unroll
            for (int r = 0; r < 4; ++r) {
                const int i = min(i0 + lGrp * 4 + r, N - 1);
                const int g_t = gt[i];
#pragma unroll
                for (int jt = 0; jt < 8; ++jt)
                    acc[jt][r] += embW2[(size_t)g_t * 128 + jt * 16 + lRow];
            }
        }
        float scl[4];
#pragma unroll
        for (int r = 0; r < 4; ++r) {
            float s = 0.f;
#pragma unroll
            for (int jt = 0; jt < 8; ++jt) {
                float v = fmaxf(acc[jt][r], 0.0f);
                s += v * v;
            }
#pragma unroll
            for (int m = 1; m <= 8; m <<= 1) s += __shfl_xor(s, m);
            scl[r] = 1.0f / fmaxf(sqrtf(s), 1e-12f);
        }
#pragma unroll
        for (int r = 0; r < 4; ++r) {
            const int i = i0 + lGrp * 4 + r;
            if (i < N) {
#pragma unroll
                for (int jt = 0; jt < 8; ++jt) {
                    float v = fmaxf(acc[jt][r], 0.0f) * scl[r];
                    if (LAST) fOut[(size_t)i * 128 + jt * 16 + lRow] = v;
                    else      hOut[(size_t)i * 128 + jt * 16 + lRow] = f2h(v);
                }
            }
        }
        const int gFirst = n2g[min(i0, N - 1)];
        const int gLast  = n2g[min(i0 + 15, N - 1)];
        if (gFirst == gLast && i0 + 15 < N) {
            if (gFirst != gCur) {
                if (gCur >= 0 && lane < 16) {
#pragma unroll
                    for (int jt = 0; jt < 8; ++jt)
                        unsafeAtomicAdd(&readout[(size_t)gCur * 384 + layerOff + jt * 16 + lane], racc[jt]);
                }
                gCur = gFirst;
#pragma unroll
                for (int jt = 0; jt < 8; ++jt) racc[jt] = 0.0f;
            }
#pragma unroll
            for (int jt = 0; jt < 8; ++jt) {
                float t = 0.f;
#pragma unroll
                for (int r = 0; r < 4; ++r) t += fmaxf(acc[jt][r], 0.0f) * scl[r];
                t += __shfl_xor(t, 16);
                t += __shfl_xor(t, 32);
                racc[jt] += t;
            }
        } else {
            if (gCur >= 0 && lane < 16) {
#pragma unroll
                for (int jt = 0; jt < 8; ++jt)
                    unsafeAtomicAdd(&readout[(size_t)gCur * 384 + layerOff + jt * 16 + lane], racc[jt]);
            }
            gCur = -1;
#pragma unroll
            for (int jt = 0; jt < 8; ++jt) racc[jt] = 0.0f;
#pragma unroll
            for (int r = 0; r < 4; ++r) {
                const int i = i0 + lGrp * 4 + r;
                if (i < N) {
                    const int g = n2g[i];
#pragma unroll
                    for (int jt = 0; jt < 8; ++jt) {
                        float v = fmaxf(acc[jt][r], 0.0f) * scl[r];
                        unsafeAtomicAdd(&readout[(size_t)g * 384 + layerOff + jt * 16 + lRow], v);
                    }
                }
            }
        }
    };

    for (int tile = t0; tile < t1; tile += 2) {
        const bool has2 = (tile + 1 < t1);
        const int i0a = tile * 16;
        const int i0b = has2 ? (tile + 1) * 16 : i0a;

        half8 afA[KC], afB[KC];
        loadA(i0a, afA);
        loadA(i0b, afB);

        floatx4 accA[8] = {}, accB[8] = {};
#pragma unroll
        for (int jt = 0; jt < 8; ++jt) {
            const int rb = (jt * 16 + lRow) * K2;
            const int sw = (jt * 16 + lRow) & 7;
#pragma unroll
            for (int kc = 0; kc < KC; ++kc) {
                half8 b = *(const half8*)(&lds[rb + (((kc * 4 + lGrp) ^ sw) * 8)]);
                accA[jt] = __builtin_amdgcn_mfma_f32_16x16x32_f16(afA[kc], b, accA[jt], 0, 0, 0);
                accB[jt] = __builtin_amdgcn_mfma_f32_16x16x32_f16(afB[kc], b, accB[jt], 0, 0, 0);
            }
        }
        epilogue(i0a, accA);
        if (has2) epilogue(i0b, accB);
    }
    if (gCur >= 0 && lane < 16) {
#pragma unroll
        for (int jt = 0; jt < 8; ++jt)
            unsafeAtomicAdd(&readout[(size_t)gCur * 384 + layerOff + jt * 16 + lane], racc[jt]);
    }
}

// ---------------------------------------------------------------------------
extern "C" void kernel_launch(void* const* d_in, const int* in_sizes, int n_in,
                              void* d_out, int out_size, void* d_ws, size_t ws_size,
                              hipStream_t stream)
{
    const int*   gate_type = (const int*)d_in[0];
    const int*   src  = (const int*)d_in[1];
    const int*   dst  = (const int*)d_in[2];
    const float* wE   = (const float*)d_in[3];
    const int*   n2g  = (const int*)d_in[4];
    const float* emb  = (const float*)d_in[5];
    const float* W1_0 = (const float*)d_in[6];
    const float* b1_0 = (const float*)d_in[7];
    const float* W2_0 = (const float*)d_in[8];
    const float* W1_1 = (const float*)d_in[9];
    const float* b1_1 = (const float*)d_in[10];
    const float* W2_1 = (const float*)d_in[11];
    const float* W1_2 = (const float*)d_in[12];
    const float* b1_2 = (const float*)d_in[13];
    const float* W2_2 = (const float*)d_in[14];

    const int N = in_sizes[0];
    const int E = in_sizes[1];
    const int NGT = in_sizes[5] / 64;
    const int cap = (E + 3 * N + 15) & ~15;

    char* ws = (char*)d_ws;
    size_t off = 0;
    auto alloc = [&](size_t bytes) { void* p = ws + off; off = (off + bytes + 255) & ~255ULL; return p; };
    _Float16* hBuf  = (_Float16*)alloc((size_t)N * 128 * 2);
    int4*     eData = (int4*)alloc(((size_t)cap + 16) * 16);
    unsigned* gInfo = (unsigned*)alloc(((size_t)cap / 4 + 4) * 4);
    int*      cnt   = (int*)alloc((size_t)N * 4);
    int*      offP  = (int*)alloc((size_t)N * 4);
    int*      cur   = (int*)alloc((size_t)N * 4);
    int*      bSums = (int*)alloc(256 * 4);
    _Float16* W1T1  = (_Float16*)alloc((size_t)128 * 128 * 2);
    _Float16* W1T2  = (_Float16*)alloc((size_t)128 * 128 * 2);
    _Float16* W2T0  = (_Float16*)alloc((size_t)128 * 128 * 2);
    _Float16* W2T1  = (_Float16*)alloc((size_t)128 * 256 * 2);
    _Float16* W2T2  = (_Float16*)alloc((size_t)128 * 256 * 2);
    _Float16* Wwh0  = (_Float16*)alloc((size_t)3 * 128 * 2);
    _Float16* Wwh1  = (_Float16*)alloc((size_t)3 * 128 * 2);
    _Float16* Wwh2  = (_Float16*)alloc((size_t)3 * 128 * 2);
    _Float16* eW1b  = (_Float16*)alloc((size_t)(NGT + 1) * 128 * 2);
    float*    eW2   = (float*)alloc((size_t)NGT * 128 * 4);
    _Float16* hW1b  = (_Float16*)alloc(((size_t)N + 1) * 128 * 2);
    size_t hn16_off = off;
    const bool h16 = (ws_size >= hn16_off + (size_t)N * 128 * 2 + 256);
    _Float16* hN16 = (_Float16*)alloc((size_t)N * 128 * 2);

    float* readout = (float*)d_out + (size_t)N * 128;  // [G,384]
    void*  hN      = h16 ? (void*)hN16 : (void*)d_out;

    const int nGroups = cap / 4;
    const int nTiles  = (N + 15) / 16;
    const int EB = 2048;                                 // edgeW blocks (4 waves)
    const int gpw = (nGroups + EB * 4 - 1) / (EB * 4);
    const int NB = 512;                                  // node blocks (4 waves)
    const int tpwN = (nTiles + NB * 4 - 1) / (NB * 4);
    const int HB = 256;                                  // hw1 blocks (8 waves)
    const int tpwH = (nTiles + HB * 8 - 1) / (HB * 8);
    const int nb = (N + 1023) / 1024;

    // ---- init + counting sort (padded to 4 per dst, 16B/slot payload) ----
    hipMemsetAsync(cnt, 0, (size_t)N * 4, stream);
    hipMemsetAsync(cur, 0, (size_t)N * 4, stream);
    hipMemsetAsync(hW1b + (size_t)N * 128, 0, 256, stream);   // zero pad row
    fill_dummy_kernel<<<(cap + 16 + 255) / 256, 256, 0, stream>>>(eData, cap + 16, N, NGT);
    hist_kernel<<<(E + 255) / 256, 256, 0, stream>>>(dst, cnt, E);
    scan1p_kernel<<<nb, 256, 0, stream>>>(cnt, offP, N, bSums);
    scan2_kernel<<<1, 256, 0, stream>>>(bSums, nb);
    scan3_kernel<<<nb, 256, 0, stream>>>(offP, N, bSums);
    scatter_kernel<<<(E + 255) / 256, 256, 0, stream>>>(src, dst, wE, gate_type,
                                                        offP, cur, eData, E);
    ginfo_kernel<<<(nGroups + 255) / 256, 256, 0, stream>>>(eData, gInfo, nGroups, N);

    // ---- weight prep ----
    embW1_kernel<<<((NGT + 1) * 128 + 255) / 256, 256, 0, stream>>>(emb, W1_0, b1_0, eW1b, NGT);
    embW2_kernel<<<(NGT * 128 + 255) / 256, 256, 0, stream>>>(emb, W2_0, eW2, NGT);
    wprep_kernel<<<(128 * 128 + 255) / 256, 256, 0, stream>>>(W1_1, W1T1, 128, 128);
    wprep_kernel<<<(128 * 128 + 255) / 256, 256, 0, stream>>>(W1_2, W1T2, 128, 128);
    wprep_kernel<<<(128 * 128 + 255) / 256, 256, 0, stream>>>(W2_0 + (size_t)64 * 128, W2T0, 128, 128);
    wprep_kernel<<<(128 * 256 + 255) / 256, 256, 0, stream>>>(W2_1, W2T1, 256, 256);
    wprep_kernel<<<(128 * 256 + 255) / 256, 256, 0, stream>>>(W2_2, W2T2, 256, 256);
    wwprep_kernel<<<2, 256, 0, stream>>>(W1_0, 64, Wwh0);
    wwprep_kernel<<<2, 256, 0, stream>>>(W1_1, 128, Wwh1);
    wwprep_kernel<<<2, 256, 0, stream>>>(W1_2, 128, Wwh2);

    if (h16) {
        hipMemsetAsync(readout, 0, (size_t)(out_size - N * 128) * 4, stream);
        hipMemsetAsync(hN16, 0, (size_t)N * 128 * 2, stream);
        // layer 0
        edgeW_kernel<true, true><<<EB, 256, 0, stream>>>(eW1b, Wwh0, eData, gInfo, hN, gpw, nGroups);
        node_kernel<true, true, false><<<NB, 256, 0, stream>>>(nullptr, hN, W2T0, eW2, gate_type, n2g,
                                                               hBuf, nullptr, readout, N, tpwN, nTiles, 0);
        // layer 1
        hw1_kernel<<<HB, 512, 0, stream>>>(hBuf, W1T1, b1_1, hW1b, N, tpwH, nTiles);
        hipMemsetAsync(hN16, 0, (size_t)N * 128 * 2, stream);
        edgeW_kernel<false, true><<<EB, 256, 0, stream>>>(hW1b, Wwh1, eData, gInfo, hN, gpw, nGroups);
        node_kernel<true, false, false><<<NB, 256, 0, stream>>>(hBuf, hN, W2T1, nullptr, nullptr, n2g,
                                                                hBuf, nullptr, readout, N, tpwN, nTiles, 128);
        // layer 2
        hw1_kernel<<<HB, 512, 0, stream>>>(hBuf, W1T2, b1_2, hW1b, N, tpwH, nTiles);
        hipMemsetAsync(hN16, 0, (size_t)N * 128 * 2, stream);
        edgeW_kernel<false, true><<<EB, 256, 0, stream>>>(hW1b, Wwh2, eData, gInfo, hN, gpw, nGroups);
        node_kernel<true, false, true><<<NB, 256, 0, stream>>>(hBuf, hN, W2T2, nullptr, nullptr, n2g,
                                                               nullptr, (float*)d_out, readout, N, tpwN, nTiles, 256);
    } else {
        hipMemsetAsync(d_out, 0, (size_t)out_size * 4, stream);
        // layer 0
        edgeW_kernel<true, false><<<EB, 256, 0, stream>>>(eW1b, Wwh0, eData, gInfo, hN, gpw, nGroups);
        node_kernel<false, true, false><<<NB, 256, 0, stream>>>(nullptr, hN, W2T0, eW2, gate_type, n2g,
                                                                hBuf, nullptr, readout, N, tpwN, nTiles, 0);
        // layer 1
        hw1_kernel<<<HB, 512, 0, stream>>>(hBuf, W1T1, b1_1, hW1b, N, tpwH, nTiles);
        hipMemsetAsync(d_out, 0, (size_t)N * 128 * 4, stream);
        edgeW_kernel<false, false><<<EB, 256, 0, stream>>>(hW1b, Wwh1, eData, gInfo, hN, gpw, nGroups);
        node_kernel<false, false, false><<<NB, 256, 0, stream>>>(hBuf, hN, W2T1, nullptr, nullptr, n2g,
                                                                 hBuf, nullptr, readout, N, tpwN, nTiles, 128);
        // layer 2
        hw1_kernel<<<HB, 512, 0, stream>>>(hBuf, W1T2, b1_2, hW1b, N, tpwH, nTiles);
        hipMemsetAsync(d_out, 0, (size_t)N * 128 * 4, stream);
        edgeW_kernel<false, false><<<EB, 256, 0, stream>>>(hW1b, Wwh2, eData, gInfo, hN, gpw, nGroups);
        node_kernel<false, false, true><<<NB, 256, 0, stream>>>(hBuf, hN, W2T2, nullptr, nullptr, n2g,
                                                                nullptr, (float*)d_out, readout, N, tpwN, nTiles, 256);
    }
}